// Round 2
// baseline (4292.485 us; speedup 1.0000x reference)
//
#include <hip/hip_runtime.h>
#include <hip/hip_bf16.h>

// ---- problem constants ----
static constexpr int B_ = 16;
static constexpr int N_ = 8192;
static constexpr int C_ = 32;     // input feature channels
static constexpr int S_ = 1024;   // NPOINT
static constexpr int K_ = 32;     // NSAMPLE
static constexpr float BN_EPS_ = 1e-5f;

__device__ __forceinline__ unsigned short f2bf(float f){
  unsigned u = __float_as_uint(f);
  unsigned r = (u + 0x7fffu + ((u >> 16) & 1u)) >> 16;
  return (unsigned short)r;
}
__device__ __forceinline__ float bflo(unsigned u){ return __int_as_float(u << 16); }
__device__ __forceinline__ float bfhi(unsigned u){ return __int_as_float(u & 0xffff0000u); }

// ---- features (B,C,N) -> featT (B,N,C) ----
__global__ __launch_bounds__(256) void transpose_kernel(const float* __restrict__ feat,
                                                        float* __restrict__ featT){
  __shared__ float tile[32][33];
  const int b = blockIdx.y;
  const int n0 = blockIdx.x * 32;
  const int tx = threadIdx.x, ty = threadIdx.y;
#pragma unroll
  for (int i = 0; i < 4; i++){
    int c = ty + i * 8;
    tile[c][tx] = feat[((size_t)b * C_ + c) * N_ + n0 + tx];
  }
  __syncthreads();
#pragma unroll
  for (int i = 0; i < 4; i++){
    int r = ty + i * 8;
    featT[((size_t)b * N_ + n0 + r) * C_ + tx] = tile[tx][r];
  }
}

// ---- furthest point sampling: 1 block per batch ----
__global__ __launch_bounds__(512) void fps_kernel(const float* __restrict__ xyz,
                                                  float* __restrict__ newxyz){
  const int b = blockIdx.x, t = threadIdx.x;
  const float* px = xyz + (size_t)b * N_ * 3;
  float X[16], Y[16], Z[16], MD[16];
#pragma unroll
  for (int j = 0; j < 16; j++){
    int p = j * 512 + t;
    X[j] = px[3 * p]; Y[j] = px[3 * p + 1]; Z[j] = px[3 * p + 2];
    MD[j] = 1e10f;
  }
  __shared__ float cen[3];
  __shared__ float wv[8];
  __shared__ int   wi[8];
  if (t == 0){
    cen[0] = px[0]; cen[1] = px[1]; cen[2] = px[2];
    size_t o = (size_t)b * S_ * 3;
    newxyz[o] = px[0]; newxyz[o + 1] = px[1]; newxyz[o + 2] = px[2];
  }
  __syncthreads();
  for (int i = 1; i < S_; i++){
    const float cx = cen[0], cy = cen[1], cz = cen[2];
    float bv = -1.f; int bi = 0x7fffffff;
#pragma unroll
    for (int j = 0; j < 16; j++){
      float dx = __fsub_rn(X[j], cx);
      float dy = __fsub_rn(Y[j], cy);
      float dz = __fsub_rn(Z[j], cz);
      float d  = __fadd_rn(__fadd_rn(__fmul_rn(dx, dx), __fmul_rn(dy, dy)), __fmul_rn(dz, dz));
      float m  = fminf(MD[j], d);
      MD[j] = m;
      if (m > bv){ bv = m; bi = j * 512 + t; }
    }
#pragma unroll
    for (int off = 1; off < 64; off <<= 1){
      float ov = __shfl_xor(bv, off);
      int   oi = __shfl_xor(bi, off);
      if (ov > bv || (ov == bv && oi < bi)){ bv = ov; bi = oi; }
    }
    if ((t & 63) == 0){ wv[t >> 6] = bv; wi[t >> 6] = bi; }
    __syncthreads();
    if (t == 0){
      float fv = wv[0]; int fi = wi[0];
#pragma unroll
      for (int w = 1; w < 8; w++){
        float ov = wv[w]; int oi = wi[w];
        if (ov > fv || (ov == fv && oi < fi)){ fv = ov; fi = oi; }
      }
      float nx = px[3 * fi], ny = px[3 * fi + 1], nz = px[3 * fi + 2];
      cen[0] = nx; cen[1] = ny; cen[2] = nz;
      size_t o = ((size_t)b * S_ + i) * 3;
      newxyz[o] = nx; newxyz[o + 1] = ny; newxyz[o + 2] = nz;
    }
    __syncthreads();
  }
}

// ---- ball query: 1 wave per centroid ----
__global__ __launch_bounds__(256) void ballq_kernel(const float* __restrict__ xyz,
                                                    const float* __restrict__ newxyz,
                                                    int* __restrict__ idxout){
  const int wave = threadIdx.x >> 6, lane = threadIdx.x & 63;
  const int cid = blockIdx.x * 4 + wave;
  const int b = cid >> 10;
  const float cx = newxyz[(size_t)cid * 3];
  const float cy = newxyz[(size_t)cid * 3 + 1];
  const float cz = newxyz[(size_t)cid * 3 + 2];
  const float* px = xyz + (size_t)b * N_ * 3;
  __shared__ int buf[4][32];
  const float r2 = 0.04f;   // fp32(double(0.2*0.2)) == 0x3D23D70A
  int have = 0;
  for (int base = 0; base < N_ && have < 32; base += 64){
    int p = base + lane;
    float dx = __fsub_rn(cx, px[3 * p]);
    float dy = __fsub_rn(cy, px[3 * p + 1]);
    float dz = __fsub_rn(cz, px[3 * p + 2]);
    float sq = __fadd_rn(__fadd_rn(__fmul_rn(dx, dx), __fmul_rn(dy, dy)), __fmul_rn(dz, dz));
    bool pred = sq < r2;
    unsigned long long m = __ballot(pred);
    if (pred){
      int pos = have + __popcll(m & ((1ull << lane) - 1ull));
      if (pos < 32) buf[wave][pos] = p;
    }
    have += (int)__popcll(m);
  }
  __syncthreads();
  if (lane < 32){
    int first = buf[wave][0];
    int v = (lane < have) ? buf[wave][lane] : first;
    idxout[(size_t)cid * 32 + lane] = v;
  }
}

// ---- LDS arena layout for the recompute pass kernels ----
template<int DEPTH>
struct PassLds {
  static constexpr int XS  = 0;                 // [32][36] f32 (x tile, col35 zeroed)
  static constexpr int W1O = XS + 32 * 36;      // [64][36] f32 (col35 zeroed)
  static constexpr int HA  = W1O + 64 * 36;     // [32][68] f32 (DEPTH>=2)
  static constexpr int W2O = HA + 32 * 68;      // [64][64] f32
  static constexpr int HB  = W2O + 64 * 64;     // [32][68] f32 (DEPTH==3)
  static constexpr int W3O = HB + 32 * 68;      // [128][64] bf16 -> 4096 f32 slots
  static constexpr int FLOATS = (DEPTH == 1) ? (W1O + 64 * 36)
                             : (DEPTH == 2) ? (W2O + 64 * 64)
                             : (W3O + 4096);    // D3: 16000 floats = 64000 B
};

// ---- fused recompute pass: chain to layer DEPTH, emit stats partials;
// ---- DEPTH==3 additionally emits pre-BN max/min over K into m3max/m3min ----
template<int DEPTH, bool FT>
__global__ __launch_bounds__(256) void pass_kernel(
    const float* __restrict__ xyz, const float* __restrict__ feat,
    const float* __restrict__ featT, const float* __restrict__ newxyz,
    const int* __restrict__ idx,
    const float* __restrict__ W1, const float* __restrict__ W2,
    const float* __restrict__ W3,
    const float* __restrict__ sab1, const float* __restrict__ sab2,
    float* __restrict__ partials,
    float* __restrict__ m3max, float* __restrict__ m3min){
  using L = PassLds<DEPTH>;
  __shared__ float sm[L::FLOATS];
  const int t = threadIdx.x;
  const int k2 = t & 31, og = t >> 5;   // row, output-group

  // ---- stage weights once per block ----
  for (int i = t; i < 64 * 36; i += 256){
    int o = i / 36, c = i - o * 36;
    sm[L::W1O + i] = (c < 35) ? W1[o * 35 + c] : 0.f;
  }
  if constexpr (DEPTH >= 2){
    for (int i = t; i < 64 * 64; i += 256) sm[L::W2O + i] = W2[i];
  }
  unsigned short* w3p = nullptr;
  if constexpr (DEPTH == 3){
    w3p = (unsigned short*)&sm[L::W3O];
    for (int i = t; i < 128 * 64; i += 256) w3p[i] = f2bf(W3[i]);
  }

  // ---- per-thread BN params for the channels this thread produces ----
  float sa1[8], sb1[8], sa2[8], sb2[8];
  if constexpr (DEPTH >= 2){
#pragma unroll
    for (int u = 0; u < 8; u++){ sa1[u] = sab1[og * 8 + u]; sb1[u] = sab1[64 + og * 8 + u]; }
  }
  if constexpr (DEPTH == 3){
#pragma unroll
    for (int u = 0; u < 8; u++){ sa2[u] = sab2[og * 8 + u]; sb2[u] = sab2[64 + og * 8 + u]; }
  }

  constexpr int US = (DEPTH == 3) ? 16 : 8;     // stats channels per thread
  float stS[US], stQ[US];
#pragma unroll
  for (int u = 0; u < US; u++){ stS[u] = 0.f; stQ[u] = 0.f; }

  for (int it = 0; it < 32; ++it){
    const int g = blockIdx.x * 32 + it;
    const int b = g >> 10;
    if constexpr (DEPTH == 1) __syncthreads();  // protect xs from prev mm1 readers

    // ---- gather x tile: [32 pts][3 rel-coords | 32 feats | 0 pad] ----
    {
      const int gk = t >> 3, gj = t & 7;
      const int id = idx[(size_t)g * 32 + gk];
      float* xr = &sm[L::XS + gk * 36];
      if constexpr (FT){
        const float4 f = *(const float4*)(featT + ((size_t)b * N_ + id) * C_ + gj * 4);
        xr[3 + gj * 4 + 0] = f.x; xr[3 + gj * 4 + 1] = f.y;
        xr[3 + gj * 4 + 2] = f.z; xr[3 + gj * 4 + 3] = f.w;
      } else {
#pragma unroll
        for (int q = 0; q < 4; q++)
          xr[3 + gj * 4 + q] = feat[((size_t)b * C_ + gj * 4 + q) * N_ + id];
      }
      if (gj == 0){
        size_t pb = ((size_t)b * N_ + id) * 3;
        xr[0] = __fsub_rn(xyz[pb + 0], newxyz[(size_t)g * 3 + 0]);
        xr[1] = __fsub_rn(xyz[pb + 1], newxyz[(size_t)g * 3 + 1]);
        xr[2] = __fsub_rn(xyz[pb + 2], newxyz[(size_t)g * 3 + 2]);
        xr[35] = 0.f;
      }
    }
    __syncthreads();

    // ---- mm1: y1[k2][og*8+u] ----
    float acc[8];
#pragma unroll
    for (int u = 0; u < 8; u++) acc[u] = 0.f;
#pragma unroll
    for (int cb = 0; cb < 36; cb += 4){
      const float4 xv = *(const float4*)&sm[L::XS + k2 * 36 + cb];
#pragma unroll
      for (int u = 0; u < 8; u++){
        const float4 wv = *(const float4*)&sm[L::W1O + (og * 8 + u) * 36 + cb];
        acc[u] = fmaf(xv.x, wv.x, acc[u]);
        acc[u] = fmaf(xv.y, wv.y, acc[u]);
        acc[u] = fmaf(xv.z, wv.z, acc[u]);
        acc[u] = fmaf(xv.w, wv.w, acc[u]);
      }
    }
    if constexpr (DEPTH == 1){
#pragma unroll
      for (int u = 0; u < 8; u++){ stS[u] += acc[u]; stQ[u] = fmaf(acc[u], acc[u], stQ[u]); }
      continue;
    }

    // ---- bn1 + relu -> hA ----
    if constexpr (DEPTH >= 2){
#pragma unroll
      for (int u = 0; u < 8; u++)
        sm[L::HA + k2 * 68 + og * 8 + u] = fmaxf(fmaf(acc[u], sa1[u], sb1[u]), 0.f);
    }
    __syncthreads();

    // ---- mm2 ----
    float acc2[8];
#pragma unroll
    for (int u = 0; u < 8; u++) acc2[u] = 0.f;
#pragma unroll
    for (int cb = 0; cb < 64; cb += 4){
      const float4 xv = *(const float4*)&sm[L::HA + k2 * 68 + cb];
#pragma unroll
      for (int u = 0; u < 8; u++){
        const float4 wv = *(const float4*)&sm[L::W2O + (og * 8 + u) * 64 + cb];
        acc2[u] = fmaf(xv.x, wv.x, acc2[u]);
        acc2[u] = fmaf(xv.y, wv.y, acc2[u]);
        acc2[u] = fmaf(xv.z, wv.z, acc2[u]);
        acc2[u] = fmaf(xv.w, wv.w, acc2[u]);
      }
    }
    if constexpr (DEPTH == 2){
#pragma unroll
      for (int u = 0; u < 8; u++){ stS[u] += acc2[u]; stQ[u] = fmaf(acc2[u], acc2[u], stQ[u]); }
      continue;
    }

    if constexpr (DEPTH == 3){
      // ---- bn2 + relu -> hB ----
#pragma unroll
      for (int u = 0; u < 8; u++)
        sm[L::HB + k2 * 68 + og * 8 + u] = fmaxf(fmaf(acc2[u], sa2[u], sb2[u]), 0.f);
      __syncthreads();

      // ---- mm3: y3[k2][og*16+u], W3 in bf16 ----
      float acc3[16];
#pragma unroll
      for (int u = 0; u < 16; u++) acc3[u] = 0.f;
#pragma unroll
      for (int cb = 0; cb < 64; cb += 4){
        const float4 xv = *(const float4*)&sm[L::HB + k2 * 68 + cb];
#pragma unroll
        for (int u = 0; u < 16; u++){
          const uint2 wp = *(const uint2*)&w3p[(og * 16 + u) * 64 + cb];
          acc3[u] = fmaf(xv.x, bflo(wp.x), acc3[u]);
          acc3[u] = fmaf(xv.y, bfhi(wp.x), acc3[u]);
          acc3[u] = fmaf(xv.z, bflo(wp.y), acc3[u]);
          acc3[u] = fmaf(xv.w, bfhi(wp.y), acc3[u]);
        }
      }
#pragma unroll
      for (int u = 0; u < 16; u++){ stS[u] += acc3[u]; stQ[u] = fmaf(acc3[u], acc3[u], stQ[u]); }

      // ---- pre-BN max/min over the 32 rows (lanes k2 within half-wave) ----
      const int s = g & 1023;
#pragma unroll
      for (int u = 0; u < 16; u++){
        float mx = acc3[u], mn = acc3[u];
#pragma unroll
        for (int m = 1; m < 32; m <<= 1){
          mx = fmaxf(mx, __shfl_xor(mx, m));
          mn = fminf(mn, __shfl_xor(mn, m));
        }
        if (k2 == 0){
          size_t o = ((size_t)b * 128 + og * 16 + u) * 1024 + s;
          m3max[o] = mx; m3min[o] = mn;
        }
      }
    }
  }

  // ---- block stats partials: reduce over rows (lanes) once at the end ----
#pragma unroll
  for (int m = 1; m < 32; m <<= 1){
#pragma unroll
    for (int u = 0; u < US; u++){
      stS[u] += __shfl_xor(stS[u], m);
      stQ[u] += __shfl_xor(stQ[u], m);
    }
  }
  if (k2 == 0){
    constexpr int CH = (DEPTH == 3) ? 128 : 64;
    float* p = partials + (size_t)blockIdx.x * (2 * CH);
    const int o0 = og * US;
#pragma unroll
    for (int u = 0; u < US; u++){ p[o0 + u] = stS[u]; p[CH + o0 + u] = stQ[u]; }
  }
}

// ---- stats stage 2: reduce 512 partial rows, emit per-channel scale/shift ----
template<int CH>
__global__ __launch_bounds__(256) void stats_fin(const float* __restrict__ partials,
                                                 const float* __restrict__ g,
                                                 const float* __restrict__ bet,
                                                 float* __restrict__ sab){
  const int t = threadIdx.x;
  __shared__ float red[2 * CH];
  if (t < 2 * CH){
    float a = 0.f;
#pragma unroll 8
    for (int r = 0; r < 512; r++) a += partials[(size_t)r * (2 * CH) + t];
    red[t] = a;
  }
  __syncthreads();
  if (t < CH){
    constexpr float inv = 1.f / (float)((size_t)B_ * S_ * K_);
    float mean = red[t] * inv;
    float var  = red[CH + t] * inv - mean * mean;
    float r    = 1.f / sqrtf(var + BN_EPS_);
    float a    = r * g[t];
    sab[t] = a;
    sab[CH + t] = bet[t] - mean * a;
  }
}

// ---- final: bn3(+relu) on the pre-BN max/min (monotone-affine dispatch) ----
__global__ __launch_bounds__(256) void final_kernel(const float* __restrict__ m3max,
                                                    const float* __restrict__ m3min,
                                                    const float* __restrict__ sab3,
                                                    float* __restrict__ outNF){
  const int i = blockIdx.x * 256 + threadIdx.x;   // over B*128*1024, layout [b][o][s]
  const int o = (i >> 10) & 127;
  const float a = sab3[o], c = sab3[128 + o];
  const float v = (a >= 0.f) ? m3max[i] : m3min[i];
  outNF[i] = fmaxf(fmaf(v, a, c), 0.f);
}

extern "C" void kernel_launch(void* const* d_in, const int* in_sizes, int n_in,
                              void* d_out, int out_size, void* d_ws, size_t ws_size,
                              hipStream_t stream){
  (void)in_sizes; (void)n_in; (void)out_size;
  const float* xyz = (const float*)d_in[0];
  const float* feat = (const float*)d_in[1];
  const float* W1 = (const float*)d_in[2];
  const float* g1 = (const float*)d_in[3];
  const float* b1 = (const float*)d_in[4];
  const float* W2 = (const float*)d_in[5];
  const float* g2 = (const float*)d_in[6];
  const float* b2 = (const float*)d_in[7];
  const float* W3 = (const float*)d_in[8];
  const float* g3 = (const float*)d_in[9];
  const float* b3 = (const float*)d_in[10];

  float* newxyz = (float*)d_out;                       // (B,S,3)
  float* outNF  = newxyz + (size_t)B_ * S_ * 3;        // (B,128,S)
  char* ws = (char*)d_ws;

  size_t off = 0;
  auto alloc = [&](size_t bytes){ size_t o = off; off += (bytes + 255) & ~(size_t)255; return o; };
  size_t o_idx  = alloc((size_t)B_ * S_ * K_ * 4);           // 2 MB
  size_t o_part = alloc((size_t)512 * 256 * 4);              // 512 KB
  size_t o_sab1 = alloc(1024);
  size_t o_sab2 = alloc(1024);
  size_t o_sab3 = alloc(1024);
  size_t o_m3mx = alloc((size_t)B_ * S_ * 128 * 4);          // 8 MB
  size_t o_m3mn = alloc((size_t)B_ * S_ * 128 * 4);          // 8 MB
  size_t core = off;
  size_t o_featT = alloc((size_t)B_ * N_ * C_ * 4);          // 16 MB (optional)
  const bool ft = ws_size >= off;
  (void)core;

  int*   idxp  = (int*)(ws + o_idx);
  float* part  = (float*)(ws + o_part);
  float* sab1  = (float*)(ws + o_sab1);
  float* sab2  = (float*)(ws + o_sab2);
  float* sab3  = (float*)(ws + o_sab3);
  float* m3mx  = (float*)(ws + o_m3mx);
  float* m3mn  = (float*)(ws + o_m3mn);
  float* featT = (float*)(ws + o_featT);

  if (ft) transpose_kernel<<<dim3(N_ / 32, B_), dim3(32, 8), 0, stream>>>(feat, featT);
  fps_kernel<<<B_, 512, 0, stream>>>(xyz, newxyz);
  ballq_kernel<<<B_ * S_ / 4, 256, 0, stream>>>(xyz, newxyz, idxp);

  if (ft){
    pass_kernel<1, true><<<512, 256, 0, stream>>>(xyz, feat, featT, newxyz, idxp,
        W1, W2, W3, sab1, sab2, part, m3mx, m3mn);
    stats_fin<64><<<1, 256, 0, stream>>>(part, g1, b1, sab1);
    pass_kernel<2, true><<<512, 256, 0, stream>>>(xyz, feat, featT, newxyz, idxp,
        W1, W2, W3, sab1, sab2, part, m3mx, m3mn);
    stats_fin<64><<<1, 256, 0, stream>>>(part, g2, b2, sab2);
    pass_kernel<3, true><<<512, 256, 0, stream>>>(xyz, feat, featT, newxyz, idxp,
        W1, W2, W3, sab1, sab2, part, m3mx, m3mn);
    stats_fin<128><<<1, 256, 0, stream>>>(part, g3, b3, sab3);
  } else {
    pass_kernel<1, false><<<512, 256, 0, stream>>>(xyz, feat, featT, newxyz, idxp,
        W1, W2, W3, sab1, sab2, part, m3mx, m3mn);
    stats_fin<64><<<1, 256, 0, stream>>>(part, g1, b1, sab1);
    pass_kernel<2, false><<<512, 256, 0, stream>>>(xyz, feat, featT, newxyz, idxp,
        W1, W2, W3, sab1, sab2, part, m3mx, m3mn);
    stats_fin<64><<<1, 256, 0, stream>>>(part, g2, b2, sab2);
    pass_kernel<3, false><<<512, 256, 0, stream>>>(xyz, feat, featT, newxyz, idxp,
        W1, W2, W3, sab1, sab2, part, m3mx, m3mn);
    stats_fin<128><<<1, 256, 0, stream>>>(part, g3, b3, sab3);
  }
  final_kernel<<<(B_ * 128 * S_) / 256, 256, 0, stream>>>(m3mx, m3mn, sab3, outNF);
}

// Round 3
// 3334.331 us; speedup vs baseline: 1.2874x; 1.2874x over previous
//
#include <hip/hip_runtime.h>
#include <hip/hip_bf16.h>

// ---- problem constants ----
static constexpr int B_ = 16;
static constexpr int N_ = 8192;
static constexpr int C_ = 32;     // input feature channels
static constexpr int S_ = 1024;   // NPOINT
static constexpr int K_ = 32;     // NSAMPLE
static constexpr float BN_EPS_ = 1e-5f;

__device__ __forceinline__ unsigned short f2bf(float f){
  unsigned u = __float_as_uint(f);
  unsigned r = (u + 0x7fffu + ((u >> 16) & 1u)) >> 16;
  return (unsigned short)r;
}
__device__ __forceinline__ float bflo(unsigned u){ return __int_as_float(u << 16); }
__device__ __forceinline__ float bfhi(unsigned u){ return __int_as_float(u & 0xffff0000u); }

// ---- features (B,C,N) -> featT (B,N,C) ----
__global__ __launch_bounds__(256) void transpose_kernel(const float* __restrict__ feat,
                                                        float* __restrict__ featT){
  __shared__ float tile[32][33];
  const int b = blockIdx.y;
  const int n0 = blockIdx.x * 32;
  const int tx = threadIdx.x, ty = threadIdx.y;
#pragma unroll
  for (int i = 0; i < 4; i++){
    int c = ty + i * 8;
    tile[c][tx] = feat[((size_t)b * C_ + c) * N_ + n0 + tx];
  }
  __syncthreads();
#pragma unroll
  for (int i = 0; i < 4; i++){
    int r = ty + i * 8;
    featT[((size_t)b * N_ + n0 + r) * C_ + tx] = tile[tx][r];
  }
}

// ---- furthest point sampling: 1 block/batch, 1 barrier/iteration ----
// Exact semantics: d = ((dx*dx+dy*dy)+dz*dz) with rn ops, min-update, global
// argmax with first-index tie-break (packed u64: value bits high, 8191-idx low).
__global__ __launch_bounds__(512) void fps_kernel(const float* __restrict__ xyz,
                                                  float* __restrict__ newxyz){
  const int b = blockIdx.x, t = threadIdx.x;
  const float* px = xyz + (size_t)b * N_ * 3;
  float X[16], Y[16], Z[16], MD[16];
#pragma unroll
  for (int j = 0; j < 16; j++){
    int p = j * 512 + t;
    X[j] = px[3 * p]; Y[j] = px[3 * p + 1]; Z[j] = px[3 * p + 2];
    MD[j] = 1e10f;
  }
  __shared__ unsigned long long rvi[2][8];
  float cx = px[0], cy = px[1], cz = px[2];
  if (t == 0){
    size_t o = (size_t)b * S_ * 3;
    newxyz[o] = cx; newxyz[o + 1] = cy; newxyz[o + 2] = cz;
  }
  for (int i = 1; i < S_; i++){
    float bv = -1.f; int bi = 0;
#pragma unroll
    for (int j = 0; j < 16; j++){
      float dx = __fsub_rn(X[j], cx);
      float dy = __fsub_rn(Y[j], cy);
      float dz = __fsub_rn(Z[j], cz);
      float d  = __fadd_rn(__fadd_rn(__fmul_rn(dx, dx), __fmul_rn(dy, dy)), __fmul_rn(dz, dz));
      float m  = fminf(MD[j], d);
      MD[j] = m;
      if (m > bv){ bv = m; bi = j * 512 + t; }   // ascending j: keeps first
    }
    // pack: larger value wins; tie -> larger (8191-bi) -> smaller bi. bv>=0 so
    // float bits are order-preserving as uint.
    unsigned long long key = ((unsigned long long)__float_as_uint(bv) << 32)
                           | (unsigned)(8191 - bi);
#pragma unroll
    for (int off = 1; off < 64; off <<= 1){
      unsigned long long ok = __shfl_xor(key, off);
      if (ok > key) key = ok;
    }
    const int p = i & 1;
    if ((t & 63) == 0) rvi[p][t >> 6] = key;
    __syncthreads();
    unsigned long long best = rvi[p][0];
#pragma unroll
    for (int w = 1; w < 8; w++){
      unsigned long long o = rvi[p][w];
      if (o > best) best = o;
    }
    const int fi = 8191 - (int)(best & 0xffffu);
    cx = px[3 * fi]; cy = px[3 * fi + 1]; cz = px[3 * fi + 2];  // broadcast, L2-warm
    if (t == 0){
      size_t o = ((size_t)b * S_ + i) * 3;
      newxyz[o] = cx; newxyz[o + 1] = cy; newxyz[o + 2] = cz;
    }
  }
}

// ---- ball query: 1 wave per centroid ----
__global__ __launch_bounds__(256) void ballq_kernel(const float* __restrict__ xyz,
                                                    const float* __restrict__ newxyz,
                                                    int* __restrict__ idxout){
  const int wave = threadIdx.x >> 6, lane = threadIdx.x & 63;
  const int cid = blockIdx.x * 4 + wave;
  const int b = cid >> 10;
  const float cx = newxyz[(size_t)cid * 3];
  const float cy = newxyz[(size_t)cid * 3 + 1];
  const float cz = newxyz[(size_t)cid * 3 + 2];
  const float* px = xyz + (size_t)b * N_ * 3;
  __shared__ int buf[4][32];
  const float r2 = 0.04f;   // fp32(double(0.2*0.2)) == 0x3D23D70A
  int have = 0;
  for (int base = 0; base < N_ && have < 32; base += 64){
    int p = base + lane;
    float dx = __fsub_rn(cx, px[3 * p]);
    float dy = __fsub_rn(cy, px[3 * p + 1]);
    float dz = __fsub_rn(cz, px[3 * p + 2]);
    float sq = __fadd_rn(__fadd_rn(__fmul_rn(dx, dx), __fmul_rn(dy, dy)), __fmul_rn(dz, dz));
    bool pred = sq < r2;
    unsigned long long m = __ballot(pred);
    if (pred){
      int pos = have + __popcll(m & ((1ull << lane) - 1ull));
      if (pos < 32) buf[wave][pos] = p;
    }
    have += (int)__popcll(m);
  }
  __syncthreads();
  if (lane < 32){
    int first = buf[wave][0];
    int v = (lane < have) ? buf[wave][lane] : first;
    idxout[(size_t)cid * 32 + lane] = v;
  }
}

// ---- LDS arena layout for the recompute pass kernels ----
template<int DEPTH>
struct PassLds {
  static constexpr int XS  = 0;                 // [32][36] f32 (x tile, col35 zeroed)
  static constexpr int W1O = XS + 32 * 36;      // [64][36] f32 (col35 zeroed)
  static constexpr int HA  = W1O + 64 * 36;     // [32][68] f32 (DEPTH>=2)
  static constexpr int W2O = HA + 32 * 68;      // [64][64] f32
  static constexpr int HB  = W2O + 64 * 64;     // [32][68] f32 (DEPTH==3)
  static constexpr int W3O = HB + 32 * 68;      // [128][64] bf16 -> 4096 f32 slots
  static constexpr int FLOATS = (DEPTH == 1) ? (W1O + 64 * 36)
                             : (DEPTH == 2) ? (W2O + 64 * 64)
                             : (W3O + 4096);    // D3: 16000 floats = 64000 B
};

// ---- fused recompute pass (512 threads: row = t&31, grp = t>>5 in [0,16)) ----
// mm1/mm2: 4 channels per thread; mm3: 8 channels per thread. No spills.
template<int DEPTH, bool FT>
__global__ __launch_bounds__(512, 1) void pass_kernel(
    const float* __restrict__ xyz, const float* __restrict__ feat,
    const float* __restrict__ featT, const float* __restrict__ newxyz,
    const int* __restrict__ idx,
    const float* __restrict__ W1, const float* __restrict__ W2,
    const float* __restrict__ W3,
    const float* __restrict__ sab1, const float* __restrict__ sab2,
    float* __restrict__ partials,
    float* __restrict__ m3max, float* __restrict__ m3min){
  using L = PassLds<DEPTH>;
  __shared__ float sm[L::FLOATS];
  const int t = threadIdx.x;
  const int row = t & 31, grp = t >> 5;   // sample-row, channel-group

  // ---- stage weights once per block ----
  for (int i = t; i < 64 * 36; i += 512){
    int o = i / 36, c = i - o * 36;
    sm[L::W1O + i] = (c < 35) ? W1[o * 35 + c] : 0.f;
  }
  if constexpr (DEPTH >= 2){
    for (int i = t; i < 64 * 64; i += 512) sm[L::W2O + i] = W2[i];
  }
  unsigned short* w3p = nullptr;
  if constexpr (DEPTH == 3){
    w3p = (unsigned short*)&sm[L::W3O];
    for (int i = t; i < 128 * 64; i += 512) w3p[i] = f2bf(W3[i]);
  }

  // ---- per-thread BN params ----
  float sa1[4], sb1[4], sa2[4], sb2[4];
  if constexpr (DEPTH >= 2){
#pragma unroll
    for (int u = 0; u < 4; u++){ sa1[u] = sab1[grp * 4 + u]; sb1[u] = sab1[64 + grp * 4 + u]; }
  }
  if constexpr (DEPTH == 3){
#pragma unroll
    for (int u = 0; u < 4; u++){ sa2[u] = sab2[grp * 4 + u]; sb2[u] = sab2[64 + grp * 4 + u]; }
  }

  constexpr int US = (DEPTH == 3) ? 8 : 4;     // stats channels per thread
  float stS[US], stQ[US];
#pragma unroll
  for (int u = 0; u < US; u++){ stS[u] = 0.f; stQ[u] = 0.f; }

  for (int it = 0; it < 32; ++it){
    const int g = blockIdx.x * 32 + it;
    const int b = g >> 10;
    if constexpr (DEPTH == 1) __syncthreads();  // protect XS from prev readers

    // ---- gather x tile: [32 pts][3 rel-coords | 32 feats | 0 pad] ----
    {
      const int id = idx[(size_t)g * 32 + row];
      float* xr = &sm[L::XS + row * 36];
      if (grp < 8){
        if constexpr (FT){
          const float4 f = *(const float4*)(featT + ((size_t)b * N_ + id) * C_ + grp * 4);
          xr[3 + grp * 4 + 0] = f.x; xr[3 + grp * 4 + 1] = f.y;
          xr[3 + grp * 4 + 2] = f.z; xr[3 + grp * 4 + 3] = f.w;
        } else {
#pragma unroll
          for (int q = 0; q < 4; q++)
            xr[3 + grp * 4 + q] = feat[((size_t)b * C_ + grp * 4 + q) * N_ + id];
        }
      } else if (grp == 8){
        size_t pb = ((size_t)b * N_ + id) * 3;
        xr[0] = __fsub_rn(xyz[pb + 0], newxyz[(size_t)g * 3 + 0]);
        xr[1] = __fsub_rn(xyz[pb + 1], newxyz[(size_t)g * 3 + 1]);
        xr[2] = __fsub_rn(xyz[pb + 2], newxyz[(size_t)g * 3 + 2]);
        xr[35] = 0.f;
      }
    }
    __syncthreads();

    // ---- mm1: y1[row][grp*4+u] ----
    float acc[4] = {0.f, 0.f, 0.f, 0.f};
#pragma unroll
    for (int cb = 0; cb < 36; cb += 4){
      const float4 xv = *(const float4*)&sm[L::XS + row * 36 + cb];
#pragma unroll
      for (int u = 0; u < 4; u++){
        const float4 wv = *(const float4*)&sm[L::W1O + (grp * 4 + u) * 36 + cb];
        acc[u] = fmaf(xv.x, wv.x, acc[u]);
        acc[u] = fmaf(xv.y, wv.y, acc[u]);
        acc[u] = fmaf(xv.z, wv.z, acc[u]);
        acc[u] = fmaf(xv.w, wv.w, acc[u]);
      }
    }
    if constexpr (DEPTH == 1){
#pragma unroll
      for (int u = 0; u < 4; u++){ stS[u] += acc[u]; stQ[u] = fmaf(acc[u], acc[u], stQ[u]); }
      continue;
    }

    if constexpr (DEPTH >= 2){
      // ---- bn1 + relu -> hA ----
#pragma unroll
      for (int u = 0; u < 4; u++)
        sm[L::HA + row * 68 + grp * 4 + u] = fmaxf(fmaf(acc[u], sa1[u], sb1[u]), 0.f);
      __syncthreads();

      // ---- mm2 ----
      float acc2[4] = {0.f, 0.f, 0.f, 0.f};
#pragma unroll
      for (int cb = 0; cb < 64; cb += 4){
        const float4 xv = *(const float4*)&sm[L::HA + row * 68 + cb];
#pragma unroll
        for (int u = 0; u < 4; u++){
          const float4 wv = *(const float4*)&sm[L::W2O + (grp * 4 + u) * 64 + cb];
          acc2[u] = fmaf(xv.x, wv.x, acc2[u]);
          acc2[u] = fmaf(xv.y, wv.y, acc2[u]);
          acc2[u] = fmaf(xv.z, wv.z, acc2[u]);
          acc2[u] = fmaf(xv.w, wv.w, acc2[u]);
        }
      }
      if constexpr (DEPTH == 2){
#pragma unroll
        for (int u = 0; u < 4; u++){ stS[u] += acc2[u]; stQ[u] = fmaf(acc2[u], acc2[u], stQ[u]); }
        continue;
      }

      if constexpr (DEPTH == 3){
        // ---- bn2 + relu -> hB ----
#pragma unroll
        for (int u = 0; u < 4; u++)
          sm[L::HB + row * 68 + grp * 4 + u] = fmaxf(fmaf(acc2[u], sa2[u], sb2[u]), 0.f);
        __syncthreads();

        // ---- mm3: y3[row][grp*8+u], W3 in bf16 ----
        float acc3[8];
#pragma unroll
        for (int u = 0; u < 8; u++) acc3[u] = 0.f;
#pragma unroll
        for (int cb = 0; cb < 64; cb += 4){
          const float4 xv = *(const float4*)&sm[L::HB + row * 68 + cb];
#pragma unroll
          for (int u = 0; u < 8; u++){
            const uint2 wp = *(const uint2*)&w3p[(grp * 8 + u) * 64 + cb];
            acc3[u] = fmaf(xv.x, bflo(wp.x), acc3[u]);
            acc3[u] = fmaf(xv.y, bfhi(wp.x), acc3[u]);
            acc3[u] = fmaf(xv.z, bflo(wp.y), acc3[u]);
            acc3[u] = fmaf(xv.w, bfhi(wp.y), acc3[u]);
          }
        }
#pragma unroll
        for (int u = 0; u < 8; u++){ stS[u] += acc3[u]; stQ[u] = fmaf(acc3[u], acc3[u], stQ[u]); }

        // ---- pre-BN max/min over the 32 rows (lanes within half-wave) ----
        const int s = g & 1023;
#pragma unroll
        for (int u = 0; u < 8; u++){
          float mx = acc3[u], mn = acc3[u];
#pragma unroll
          for (int m = 1; m < 32; m <<= 1){
            mx = fmaxf(mx, __shfl_xor(mx, m));
            mn = fminf(mn, __shfl_xor(mn, m));
          }
          if (row == 0){
            size_t o = ((size_t)b * 128 + grp * 8 + u) * 1024 + s;
            m3max[o] = mx; m3min[o] = mn;
          }
        }
      }
    }
  }

  // ---- block stats partials: reduce over rows (half-wave lanes) ----
#pragma unroll
  for (int m = 1; m < 32; m <<= 1){
#pragma unroll
    for (int u = 0; u < US; u++){
      stS[u] += __shfl_xor(stS[u], m);
      stQ[u] += __shfl_xor(stQ[u], m);
    }
  }
  if (row == 0){
    constexpr int CH = (DEPTH == 3) ? 128 : 64;
    float* p = partials + (size_t)blockIdx.x * (2 * CH);
    const int o0 = grp * US;
#pragma unroll
    for (int u = 0; u < US; u++){ p[o0 + u] = stS[u]; p[CH + o0 + u] = stQ[u]; }
  }
}

// ---- stats stage 2: reduce 512 partial rows, emit per-channel scale/shift ----
template<int CH>
__global__ __launch_bounds__(256) void stats_fin(const float* __restrict__ partials,
                                                 const float* __restrict__ g,
                                                 const float* __restrict__ bet,
                                                 float* __restrict__ sab){
  const int t = threadIdx.x;
  __shared__ float red[2 * CH];
  if (t < 2 * CH){
    float a = 0.f;
#pragma unroll 8
    for (int r = 0; r < 512; r++) a += partials[(size_t)r * (2 * CH) + t];
    red[t] = a;
  }
  __syncthreads();
  if (t < CH){
    constexpr float inv = 1.f / (float)((size_t)B_ * S_ * K_);
    float mean = red[t] * inv;
    float var  = red[CH + t] * inv - mean * mean;
    float r    = 1.f / sqrtf(var + BN_EPS_);
    float a    = r * g[t];
    sab[t] = a;
    sab[CH + t] = bet[t] - mean * a;
  }
}

// ---- final: bn3(+relu) on the pre-BN max/min (monotone-affine dispatch) ----
__global__ __launch_bounds__(256) void final_kernel(const float* __restrict__ m3max,
                                                    const float* __restrict__ m3min,
                                                    const float* __restrict__ sab3,
                                                    float* __restrict__ outNF){
  const int i = blockIdx.x * 256 + threadIdx.x;   // over B*128*1024, layout [b][o][s]
  const int o = (i >> 10) & 127;
  const float a = sab3[o], c = sab3[128 + o];
  const float v = (a >= 0.f) ? m3max[i] : m3min[i];
  outNF[i] = fmaxf(fmaf(v, a, c), 0.f);
}

extern "C" void kernel_launch(void* const* d_in, const int* in_sizes, int n_in,
                              void* d_out, int out_size, void* d_ws, size_t ws_size,
                              hipStream_t stream){
  (void)in_sizes; (void)n_in; (void)out_size;
  const float* xyz = (const float*)d_in[0];
  const float* feat = (const float*)d_in[1];
  const float* W1 = (const float*)d_in[2];
  const float* g1 = (const float*)d_in[3];
  const float* b1 = (const float*)d_in[4];
  const float* W2 = (const float*)d_in[5];
  const float* g2 = (const float*)d_in[6];
  const float* b2 = (const float*)d_in[7];
  const float* W3 = (const float*)d_in[8];
  const float* g3 = (const float*)d_in[9];
  const float* b3 = (const float*)d_in[10];

  float* newxyz = (float*)d_out;                       // (B,S,3)
  float* outNF  = newxyz + (size_t)B_ * S_ * 3;        // (B,128,S)
  char* ws = (char*)d_ws;

  size_t off = 0;
  auto alloc = [&](size_t bytes){ size_t o = off; off += (bytes + 255) & ~(size_t)255; return o; };
  size_t o_idx  = alloc((size_t)B_ * S_ * K_ * 4);           // 2 MB
  size_t o_part = alloc((size_t)512 * 256 * 4);              // 512 KB
  size_t o_sab1 = alloc(1024);
  size_t o_sab2 = alloc(1024);
  size_t o_sab3 = alloc(1024);
  size_t o_m3mx = alloc((size_t)B_ * S_ * 128 * 4);          // 8 MB
  size_t o_m3mn = alloc((size_t)B_ * S_ * 128 * 4);          // 8 MB
  size_t o_featT = alloc((size_t)B_ * N_ * C_ * 4);          // 16 MB (optional)
  const bool ft = ws_size >= off;

  int*   idxp  = (int*)(ws + o_idx);
  float* part  = (float*)(ws + o_part);
  float* sab1  = (float*)(ws + o_sab1);
  float* sab2  = (float*)(ws + o_sab2);
  float* sab3  = (float*)(ws + o_sab3);
  float* m3mx  = (float*)(ws + o_m3mx);
  float* m3mn  = (float*)(ws + o_m3mn);
  float* featT = (float*)(ws + o_featT);

  if (ft) transpose_kernel<<<dim3(N_ / 32, B_), dim3(32, 8), 0, stream>>>(feat, featT);
  fps_kernel<<<B_, 512, 0, stream>>>(xyz, newxyz);
  ballq_kernel<<<B_ * S_ / 4, 256, 0, stream>>>(xyz, newxyz, idxp);

  if (ft){
    pass_kernel<1, true><<<512, 512, 0, stream>>>(xyz, feat, featT, newxyz, idxp,
        W1, W2, W3, sab1, sab2, part, m3mx, m3mn);
    stats_fin<64><<<1, 256, 0, stream>>>(part, g1, b1, sab1);
    pass_kernel<2, true><<<512, 512, 0, stream>>>(xyz, feat, featT, newxyz, idxp,
        W1, W2, W3, sab1, sab2, part, m3mx, m3mn);
    stats_fin<64><<<1, 256, 0, stream>>>(part, g2, b2, sab2);
    pass_kernel<3, true><<<512, 512, 0, stream>>>(xyz, feat, featT, newxyz, idxp,
        W1, W2, W3, sab1, sab2, part, m3mx, m3mn);
    stats_fin<128><<<1, 256, 0, stream>>>(part, g3, b3, sab3);
  } else {
    pass_kernel<1, false><<<512, 512, 0, stream>>>(xyz, feat, featT, newxyz, idxp,
        W1, W2, W3, sab1, sab2, part, m3mx, m3mn);
    stats_fin<64><<<1, 256, 0, stream>>>(part, g1, b1, sab1);
    pass_kernel<2, false><<<512, 512, 0, stream>>>(xyz, feat, featT, newxyz, idxp,
        W1, W2, W3, sab1, sab2, part, m3mx, m3mn);
    stats_fin<64><<<1, 256, 0, stream>>>(part, g2, b2, sab2);
    pass_kernel<3, false><<<512, 512, 0, stream>>>(xyz, feat, featT, newxyz, idxp,
        W1, W2, W3, sab1, sab2, part, m3mx, m3mn);
    stats_fin<128><<<1, 256, 0, stream>>>(part, g3, b3, sab3);
  }
  final_kernel<<<(B_ * 128 * S_) / 256, 256, 0, stream>>>(m3mx, m3mn, sab3, outNF);
}

// Round 4
// 2497.095 us; speedup vs baseline: 1.7190x; 1.3353x over previous
//
#include <hip/hip_runtime.h>
#include <hip/hip_bf16.h>

// ---- problem constants ----
static constexpr int B_ = 16;
static constexpr int N_ = 8192;
static constexpr int C_ = 32;     // input feature channels
static constexpr int S_ = 1024;   // NPOINT
static constexpr int K_ = 32;     // NSAMPLE
static constexpr float BN_EPS_ = 1e-5f;

__device__ __forceinline__ unsigned short f2bf(float f){
  unsigned u = __float_as_uint(f);
  unsigned r = (u + 0x7fffu + ((u >> 16) & 1u)) >> 16;
  return (unsigned short)r;
}
__device__ __forceinline__ float bflo(unsigned u){ return __int_as_float(u << 16); }
__device__ __forceinline__ float bfhi(unsigned u){ return __int_as_float(u & 0xffff0000u); }
__device__ __forceinline__ float bfu(unsigned short u){ return __int_as_float(((unsigned)u) << 16); }

// ---- features (B,C,N) f32 -> featT (B,N,C) bf16 ----
__global__ __launch_bounds__(256) void transpose_kernel(const float* __restrict__ feat,
                                                        unsigned short* __restrict__ featT){
  __shared__ float tile[32][33];
  const int b = blockIdx.y;
  const int n0 = blockIdx.x * 32;
  const int tx = threadIdx.x, ty = threadIdx.y;
#pragma unroll
  for (int i = 0; i < 4; i++){
    int c = ty + i * 8;
    tile[c][tx] = feat[((size_t)b * C_ + c) * N_ + n0 + tx];
  }
  __syncthreads();
#pragma unroll
  for (int i = 0; i < 4; i++){
    int r = ty + i * 8;
    featT[((size_t)b * N_ + n0 + r) * C_ + tx] = f2bf(tile[tx][r]);
  }
}

// ---- furthest point sampling: 1 block/batch, 1 barrier/iter, no global reload ----
// Exact semantics: d = ((dx*dx+dy*dy)+dz*dz) rn ops, min-update, argmax with
// first-index tie-break (packed u64 key: value bits high, 8191-idx low).
// Winner's coordinates ride along the butterfly -> centroid via LDS broadcast.
__global__ __launch_bounds__(512) void fps_kernel(const float* __restrict__ xyz,
                                                  float* __restrict__ newxyz){
  const int b = blockIdx.x, t = threadIdx.x;
  const float* px = xyz + (size_t)b * N_ * 3;
  float X[16], Y[16], Z[16], MD[16];
#pragma unroll
  for (int j = 0; j < 16; j++){
    int p = j * 512 + t;
    X[j] = px[3 * p]; Y[j] = px[3 * p + 1]; Z[j] = px[3 * p + 2];
    MD[j] = 1e10f;
  }
  __shared__ unsigned long long rvi[2][8];
  __shared__ float rx[2][8], ry[2][8], rz[2][8];
  float cx = px[0], cy = px[1], cz = px[2];
  if (t == 0){
    size_t o = (size_t)b * S_ * 3;
    newxyz[o] = cx; newxyz[o + 1] = cy; newxyz[o + 2] = cz;
  }
  for (int i = 1; i < S_; i++){
    float bv = -1.f; int bi = 0;
    float bx = 0.f, by = 0.f, bz = 0.f;
#pragma unroll
    for (int j = 0; j < 16; j++){
      float dx = __fsub_rn(X[j], cx);
      float dy = __fsub_rn(Y[j], cy);
      float dz = __fsub_rn(Z[j], cz);
      float d  = __fadd_rn(__fadd_rn(__fmul_rn(dx, dx), __fmul_rn(dy, dy)), __fmul_rn(dz, dz));
      float m  = fminf(MD[j], d);
      MD[j] = m;
      if (m > bv){ bv = m; bi = j * 512 + t; bx = X[j]; by = Y[j]; bz = Z[j]; }
    }
    // key: larger value wins; tie -> larger (8191-bi) -> smaller bi. bv>=0 so
    // float bits are order-preserving as uint.
    unsigned long long key = ((unsigned long long)__float_as_uint(bv) << 32)
                           | (unsigned)(8191 - bi);
#pragma unroll
    for (int off = 1; off < 64; off <<= 1){
      unsigned long long ok = __shfl_xor(key, off);
      float ox = __shfl_xor(bx, off);
      float oy = __shfl_xor(by, off);
      float oz = __shfl_xor(bz, off);
      if (ok > key){ key = ok; bx = ox; by = oy; bz = oz; }
    }
    const int p = i & 1;
    if ((t & 63) == 0){
      int w = t >> 6;
      rvi[p][w] = key; rx[p][w] = bx; ry[p][w] = by; rz[p][w] = bz;
    }
    __syncthreads();
    unsigned long long best = rvi[p][0]; int wb = 0;
#pragma unroll
    for (int w = 1; w < 8; w++){
      unsigned long long o = rvi[p][w];
      if (o > best){ best = o; wb = w; }
    }
    cx = rx[p][wb]; cy = ry[p][wb]; cz = rz[p][wb];
    if (t == 0){
      size_t o = ((size_t)b * S_ + i) * 3;
      newxyz[o] = cx; newxyz[o + 1] = cy; newxyz[o + 2] = cz;
    }
  }
}

// ---- ball query: 1 wave per centroid ----
__global__ __launch_bounds__(256) void ballq_kernel(const float* __restrict__ xyz,
                                                    const float* __restrict__ newxyz,
                                                    int* __restrict__ idxout){
  const int wave = threadIdx.x >> 6, lane = threadIdx.x & 63;
  const int cid = blockIdx.x * 4 + wave;
  const int b = cid >> 10;
  const float cx = newxyz[(size_t)cid * 3];
  const float cy = newxyz[(size_t)cid * 3 + 1];
  const float cz = newxyz[(size_t)cid * 3 + 2];
  const float* px = xyz + (size_t)b * N_ * 3;
  __shared__ int buf[4][32];
  const float r2 = 0.04f;   // fp32(double(0.2*0.2)) == 0x3D23D70A
  int have = 0;
  for (int base = 0; base < N_ && have < 32; base += 64){
    int p = base + lane;
    float dx = __fsub_rn(cx, px[3 * p]);
    float dy = __fsub_rn(cy, px[3 * p + 1]);
    float dz = __fsub_rn(cz, px[3 * p + 2]);
    float sq = __fadd_rn(__fadd_rn(__fmul_rn(dx, dx), __fmul_rn(dy, dy)), __fmul_rn(dz, dz));
    bool pred = sq < r2;
    unsigned long long m = __ballot(pred);
    if (pred){
      int pos = have + __popcll(m & ((1ull << lane) - 1ull));
      if (pos < 32) buf[wave][pos] = p;
    }
    have += (int)__popcll(m);
  }
  __syncthreads();
  if (lane < 32){
    int first = buf[wave][0];
    int v = (lane < have) ? buf[wave][lane] : first;
    idxout[(size_t)cid * 32 + lane] = v;
  }
}

// ---- LDS arena layout for the recompute pass kernels ----
template<int DEPTH>
struct PassLds {
  static constexpr int XS  = 0;                 // [32][36] f32 (x tile, col35 zeroed)
  static constexpr int W1O = XS + 32 * 36;      // [64][36] f32 (col35 zeroed)
  static constexpr int HA  = W1O + 64 * 36;     // [32][68] f32 (DEPTH>=2)
  static constexpr int W2O = HA + 32 * 68;      // [64][64] f32
  static constexpr int HB  = W2O + 64 * 64;     // [32][68] f32 (DEPTH==3)
  static constexpr int W3O = HB + 32 * 68;      // [128][64] bf16 -> 4096 f32 slots
  static constexpr int FLOATS = (DEPTH == 1) ? (W1O + 64 * 36)
                             : (DEPTH == 2) ? (W2O + 64 * 64)
                             : (W3O + 4096);    // D3: 16000 floats = 64000 B
};

// ---- fused recompute pass (512 threads: row = t&31, grp = t>>5 in [0,16)) ----
template<int DEPTH, bool FT>
__global__ __launch_bounds__(512) void pass_kernel(
    const float* __restrict__ xyz, const float* __restrict__ feat,
    const unsigned short* __restrict__ featT, const float* __restrict__ newxyz,
    const int* __restrict__ idx,
    const float* __restrict__ W1, const float* __restrict__ W2,
    const float* __restrict__ W3,
    const float* __restrict__ sab1, const float* __restrict__ sab2,
    float* __restrict__ partials,
    unsigned short* __restrict__ m3max, unsigned short* __restrict__ m3min){
  using L = PassLds<DEPTH>;
  __shared__ float sm[L::FLOATS];
  const int t = threadIdx.x;
  const int row = t & 31, grp = t >> 5;   // sample-row, channel-group

  // ---- stage weights once per block ----
  for (int i = t; i < 64 * 36; i += 512){
    int o = i / 36, c = i - o * 36;
    sm[L::W1O + i] = (c < 35) ? W1[o * 35 + c] : 0.f;
  }
  if constexpr (DEPTH >= 2){
    for (int i = t; i < 64 * 64; i += 512) sm[L::W2O + i] = W2[i];
  }
  unsigned short* w3p = nullptr;
  if constexpr (DEPTH == 3){
    w3p = (unsigned short*)&sm[L::W3O];
    for (int i = t; i < 128 * 64; i += 512) w3p[i] = f2bf(W3[i]);
  }

  // ---- per-thread BN params ----
  float sa1[4], sb1[4], sa2[4], sb2[4];
  if constexpr (DEPTH >= 2){
#pragma unroll
    for (int u = 0; u < 4; u++){ sa1[u] = sab1[grp * 4 + u]; sb1[u] = sab1[64 + grp * 4 + u]; }
  }
  if constexpr (DEPTH == 3){
#pragma unroll
    for (int u = 0; u < 4; u++){ sa2[u] = sab2[grp * 4 + u]; sb2[u] = sab2[64 + grp * 4 + u]; }
  }

  constexpr int US = (DEPTH == 3) ? 8 : 4;     // stats channels per thread
  float stS[US], stQ[US];
#pragma unroll
  for (int u = 0; u < US; u++){ stS[u] = 0.f; stQ[u] = 0.f; }

  for (int it = 0; it < 32; ++it){
    const int g = blockIdx.x * 32 + it;
    const int b = g >> 10;
    if constexpr (DEPTH == 1) __syncthreads();  // protect XS from prev readers

    // ---- gather x tile: [32 pts][3 rel-coords | 32 feats | 0 pad] ----
    {
      float* xr = &sm[L::XS + row * 36];
      if constexpr (FT){
        if (grp < 4){
          const int id = idx[(size_t)g * 32 + row];
          const uint4 f = *(const uint4*)(featT + ((size_t)b * N_ + id) * C_ + grp * 8);
          xr[3 + grp * 8 + 0] = bflo(f.x); xr[3 + grp * 8 + 1] = bfhi(f.x);
          xr[3 + grp * 8 + 2] = bflo(f.y); xr[3 + grp * 8 + 3] = bfhi(f.y);
          xr[3 + grp * 8 + 4] = bflo(f.z); xr[3 + grp * 8 + 5] = bfhi(f.z);
          xr[3 + grp * 8 + 6] = bflo(f.w); xr[3 + grp * 8 + 7] = bfhi(f.w);
        } else if (grp == 4){
          const int id = idx[(size_t)g * 32 + row];
          size_t pb = ((size_t)b * N_ + id) * 3;
          xr[0] = __fsub_rn(xyz[pb + 0], newxyz[(size_t)g * 3 + 0]);
          xr[1] = __fsub_rn(xyz[pb + 1], newxyz[(size_t)g * 3 + 1]);
          xr[2] = __fsub_rn(xyz[pb + 2], newxyz[(size_t)g * 3 + 2]);
          xr[35] = 0.f;
        }
      } else {
        if (grp < 8){
          const int id = idx[(size_t)g * 32 + row];
#pragma unroll
          for (int q = 0; q < 4; q++)
            xr[3 + grp * 4 + q] = feat[((size_t)b * C_ + grp * 4 + q) * N_ + id];
        } else if (grp == 8){
          const int id = idx[(size_t)g * 32 + row];
          size_t pb = ((size_t)b * N_ + id) * 3;
          xr[0] = __fsub_rn(xyz[pb + 0], newxyz[(size_t)g * 3 + 0]);
          xr[1] = __fsub_rn(xyz[pb + 1], newxyz[(size_t)g * 3 + 1]);
          xr[2] = __fsub_rn(xyz[pb + 2], newxyz[(size_t)g * 3 + 2]);
          xr[35] = 0.f;
        }
      }
    }
    __syncthreads();

    // ---- mm1: y1[row][grp*4+u] ----
    float acc[4] = {0.f, 0.f, 0.f, 0.f};
#pragma unroll 3
    for (int cb = 0; cb < 36; cb += 4){
      const float4 xv = *(const float4*)&sm[L::XS + row * 36 + cb];
#pragma unroll
      for (int u = 0; u < 4; u++){
        const float4 wv = *(const float4*)&sm[L::W1O + (grp * 4 + u) * 36 + cb];
        acc[u] = fmaf(xv.x, wv.x, acc[u]);
        acc[u] = fmaf(xv.y, wv.y, acc[u]);
        acc[u] = fmaf(xv.z, wv.z, acc[u]);
        acc[u] = fmaf(xv.w, wv.w, acc[u]);
      }
    }
    if constexpr (DEPTH == 1){
#pragma unroll
      for (int u = 0; u < 4; u++){ stS[u] += acc[u]; stQ[u] = fmaf(acc[u], acc[u], stQ[u]); }
      continue;
    }

    if constexpr (DEPTH >= 2){
      // ---- bn1 + relu -> hA ----
#pragma unroll
      for (int u = 0; u < 4; u++)
        sm[L::HA + row * 68 + grp * 4 + u] = fmaxf(fmaf(acc[u], sa1[u], sb1[u]), 0.f);
      __syncthreads();

      // ---- mm2 ----
      float acc2[4] = {0.f, 0.f, 0.f, 0.f};
#pragma unroll 4
      for (int cb = 0; cb < 64; cb += 4){
        const float4 xv = *(const float4*)&sm[L::HA + row * 68 + cb];
#pragma unroll
        for (int u = 0; u < 4; u++){
          const float4 wv = *(const float4*)&sm[L::W2O + (grp * 4 + u) * 64 + cb];
          acc2[u] = fmaf(xv.x, wv.x, acc2[u]);
          acc2[u] = fmaf(xv.y, wv.y, acc2[u]);
          acc2[u] = fmaf(xv.z, wv.z, acc2[u]);
          acc2[u] = fmaf(xv.w, wv.w, acc2[u]);
        }
      }
      if constexpr (DEPTH == 2){
#pragma unroll
        for (int u = 0; u < 4; u++){ stS[u] += acc2[u]; stQ[u] = fmaf(acc2[u], acc2[u], stQ[u]); }
        continue;
      }

      if constexpr (DEPTH == 3){
        // ---- bn2 + relu -> hB ----
#pragma unroll
        for (int u = 0; u < 4; u++)
          sm[L::HB + row * 68 + grp * 4 + u] = fmaxf(fmaf(acc2[u], sa2[u], sb2[u]), 0.f);
        __syncthreads();

        // ---- mm3: y3[row][grp*8+u], W3 bf16 in LDS ----
        float acc3[8];
#pragma unroll
        for (int u = 0; u < 8; u++) acc3[u] = 0.f;
#pragma unroll 2
        for (int cb = 0; cb < 64; cb += 4){
          const float4 xv = *(const float4*)&sm[L::HB + row * 68 + cb];
#pragma unroll
          for (int u = 0; u < 8; u++){
            const uint2 wp = *(const uint2*)&w3p[(grp * 8 + u) * 64 + cb];
            acc3[u] = fmaf(xv.x, bflo(wp.x), acc3[u]);
            acc3[u] = fmaf(xv.y, bfhi(wp.x), acc3[u]);
            acc3[u] = fmaf(xv.z, bflo(wp.y), acc3[u]);
            acc3[u] = fmaf(xv.w, bfhi(wp.y), acc3[u]);
          }
        }
#pragma unroll
        for (int u = 0; u < 8; u++){ stS[u] += acc3[u]; stQ[u] = fmaf(acc3[u], acc3[u], stQ[u]); }

        // ---- pre-BN max/min over the 32 rows (lanes within half-wave) ----
        const int s = g & 1023;
#pragma unroll
        for (int u = 0; u < 8; u++){
          float mx = acc3[u], mn = acc3[u];
#pragma unroll
          for (int m = 1; m < 32; m <<= 1){
            mx = fmaxf(mx, __shfl_xor(mx, m));
            mn = fminf(mn, __shfl_xor(mn, m));
          }
          if (row == 0){
            size_t o = ((size_t)b * 128 + grp * 8 + u) * 1024 + s;
            m3max[o] = f2bf(mx); m3min[o] = f2bf(mn);
          }
        }
      }
    }
  }

  // ---- block stats partials: reduce over rows (half-wave lanes) ----
#pragma unroll
  for (int m = 1; m < 32; m <<= 1){
#pragma unroll
    for (int u = 0; u < US; u++){
      stS[u] += __shfl_xor(stS[u], m);
      stQ[u] += __shfl_xor(stQ[u], m);
    }
  }
  if (row == 0){
    constexpr int CH = (DEPTH == 3) ? 128 : 64;
    float* p = partials + (size_t)blockIdx.x * (2 * CH);
    const int o0 = grp * US;
#pragma unroll
    for (int u = 0; u < US; u++){ p[o0 + u] = stS[u]; p[CH + o0 + u] = stQ[u]; }
  }
}

// ---- stats stage 2: reduce 512 partial rows, emit per-channel scale/shift ----
template<int CH>
__global__ __launch_bounds__(256) void stats_fin(const float* __restrict__ partials,
                                                 const float* __restrict__ g,
                                                 const float* __restrict__ bet,
                                                 float* __restrict__ sab){
  const int t = threadIdx.x;
  __shared__ float red[2 * CH];
  if (t < 2 * CH){
    float a = 0.f;
#pragma unroll 8
    for (int r = 0; r < 512; r++) a += partials[(size_t)r * (2 * CH) + t];
    red[t] = a;
  }
  __syncthreads();
  if (t < CH){
    constexpr float inv = 1.f / (float)((size_t)B_ * S_ * K_);
    float mean = red[t] * inv;
    float var  = red[CH + t] * inv - mean * mean;
    float r    = 1.f / sqrtf(var + BN_EPS_);
    float a    = r * g[t];
    sab[t] = a;
    sab[CH + t] = bet[t] - mean * a;
  }
}

// ---- final: bn3(+relu) on bf16 pre-BN max/min (monotone-affine dispatch) ----
__global__ __launch_bounds__(256) void final_kernel(const unsigned short* __restrict__ m3max,
                                                    const unsigned short* __restrict__ m3min,
                                                    const float* __restrict__ sab3,
                                                    float* __restrict__ outNF){
  const int q = blockIdx.x * 256 + threadIdx.x;   // quad index over B*128*1024/4
  const int e = q * 4;
  const int o = (e >> 10) & 127;
  const float a = sab3[o], c = sab3[128 + o];
  const ushort4 mx = ((const ushort4*)m3max)[q];
  const ushort4 mn = ((const ushort4*)m3min)[q];
  float4 r;
  r.x = fmaxf(fmaf(bfu(a >= 0.f ? mx.x : mn.x), a, c), 0.f);
  r.y = fmaxf(fmaf(bfu(a >= 0.f ? mx.y : mn.y), a, c), 0.f);
  r.z = fmaxf(fmaf(bfu(a >= 0.f ? mx.z : mn.z), a, c), 0.f);
  r.w = fmaxf(fmaf(bfu(a >= 0.f ? mx.w : mn.w), a, c), 0.f);
  ((float4*)outNF)[q] = r;
}

extern "C" void kernel_launch(void* const* d_in, const int* in_sizes, int n_in,
                              void* d_out, int out_size, void* d_ws, size_t ws_size,
                              hipStream_t stream){
  (void)in_sizes; (void)n_in; (void)out_size;
  const float* xyz = (const float*)d_in[0];
  const float* feat = (const float*)d_in[1];
  const float* W1 = (const float*)d_in[2];
  const float* g1 = (const float*)d_in[3];
  const float* b1 = (const float*)d_in[4];
  const float* W2 = (const float*)d_in[5];
  const float* g2 = (const float*)d_in[6];
  const float* b2 = (const float*)d_in[7];
  const float* W3 = (const float*)d_in[8];
  const float* g3 = (const float*)d_in[9];
  const float* b3 = (const float*)d_in[10];

  float* newxyz = (float*)d_out;                       // (B,S,3)
  float* outNF  = newxyz + (size_t)B_ * S_ * 3;        // (B,128,S)
  char* ws = (char*)d_ws;

  size_t off = 0;
  auto alloc = [&](size_t bytes){ size_t o = off; off += (bytes + 255) & ~(size_t)255; return o; };
  size_t o_idx  = alloc((size_t)B_ * S_ * K_ * 4);           // 2 MB
  size_t o_part = alloc((size_t)512 * 256 * 4);              // 512 KB
  size_t o_sab1 = alloc(1024);
  size_t o_sab2 = alloc(1024);
  size_t o_sab3 = alloc(1024);
  size_t o_m3mx = alloc((size_t)B_ * S_ * 128 * 2);          // 4 MB (bf16)
  size_t o_m3mn = alloc((size_t)B_ * S_ * 128 * 2);          // 4 MB (bf16)
  size_t o_featT = alloc((size_t)B_ * N_ * C_ * 2);          // 8 MB (bf16)
  const bool ft = ws_size >= off;                            // 19.4 MB total

  int*   idxp  = (int*)(ws + o_idx);
  float* part  = (float*)(ws + o_part);
  float* sab1  = (float*)(ws + o_sab1);
  float* sab2  = (float*)(ws + o_sab2);
  float* sab3  = (float*)(ws + o_sab3);
  unsigned short* m3mx  = (unsigned short*)(ws + o_m3mx);
  unsigned short* m3mn  = (unsigned short*)(ws + o_m3mn);
  unsigned short* featT = (unsigned short*)(ws + o_featT);

  if (ft) transpose_kernel<<<dim3(N_ / 32, B_), dim3(32, 8), 0, stream>>>(feat, featT);
  fps_kernel<<<B_, 512, 0, stream>>>(xyz, newxyz);
  ballq_kernel<<<B_ * S_ / 4, 256, 0, stream>>>(xyz, newxyz, idxp);

  if (ft){
    pass_kernel<1, true><<<512, 512, 0, stream>>>(xyz, feat, featT, newxyz, idxp,
        W1, W2, W3, sab1, sab2, part, m3mx, m3mn);
    stats_fin<64><<<1, 256, 0, stream>>>(part, g1, b1, sab1);
    pass_kernel<2, true><<<512, 512, 0, stream>>>(xyz, feat, featT, newxyz, idxp,
        W1, W2, W3, sab1, sab2, part, m3mx, m3mn);
    stats_fin<64><<<1, 256, 0, stream>>>(part, g2, b2, sab2);
    pass_kernel<3, true><<<512, 512, 0, stream>>>(xyz, feat, featT, newxyz, idxp,
        W1, W2, W3, sab1, sab2, part, m3mx, m3mn);
    stats_fin<128><<<1, 256, 0, stream>>>(part, g3, b3, sab3);
  } else {
    pass_kernel<1, false><<<512, 512, 0, stream>>>(xyz, feat, featT, newxyz, idxp,
        W1, W2, W3, sab1, sab2, part, m3mx, m3mn);
    stats_fin<64><<<1, 256, 0, stream>>>(part, g1, b1, sab1);
    pass_kernel<2, false><<<512, 512, 0, stream>>>(xyz, feat, featT, newxyz, idxp,
        W1, W2, W3, sab1, sab2, part, m3mx, m3mn);
    stats_fin<64><<<1, 256, 0, stream>>>(part, g2, b2, sab2);
    pass_kernel<3, false><<<512, 512, 0, stream>>>(xyz, feat, featT, newxyz, idxp,
        W1, W2, W3, sab1, sab2, part, m3mx, m3mn);
    stats_fin<128><<<1, 256, 0, stream>>>(part, g3, b3, sab3);
  }
  final_kernel<<<(B_ * 128 * S_) / 1024, 256, 0, stream>>>(m3mx, m3mn, sab3, outNF);
}

// Round 5
// 2066.022 us; speedup vs baseline: 2.0777x; 1.2086x over previous
//
#include <hip/hip_runtime.h>
#include <hip/hip_bf16.h>

// ---- problem constants ----
static constexpr int B_ = 16;
static constexpr int N_ = 8192;
static constexpr int C_ = 32;     // input feature channels
static constexpr int S_ = 1024;   // NPOINT
static constexpr int K_ = 32;     // NSAMPLE
static constexpr float BN_EPS_ = 1e-5f;

__device__ __forceinline__ unsigned short f2bf(float f){
  unsigned u = __float_as_uint(f);
  unsigned r = (u + 0x7fffu + ((u >> 16) & 1u)) >> 16;
  return (unsigned short)r;
}
__device__ __forceinline__ float bflo(unsigned u){ return __int_as_float(u << 16); }
__device__ __forceinline__ float bfhi(unsigned u){ return __int_as_float(u & 0xffff0000u); }
__device__ __forceinline__ float bfu(unsigned short u){ return __int_as_float(((unsigned)u) << 16); }

// ---- features (B,C,N) f32 -> featT (B,N,C) bf16 ----
__global__ __launch_bounds__(256) void transpose_kernel(const float* __restrict__ feat,
                                                        unsigned short* __restrict__ featT){
  __shared__ float tile[32][33];
  const int b = blockIdx.y;
  const int n0 = blockIdx.x * 32;
  const int tx = threadIdx.x, ty = threadIdx.y;
#pragma unroll
  for (int i = 0; i < 4; i++){
    int c = ty + i * 8;
    tile[c][tx] = feat[((size_t)b * C_ + c) * N_ + n0 + tx];
  }
  __syncthreads();
#pragma unroll
  for (int i = 0; i < 4; i++){
    int r = ty + i * 8;
    featT[((size_t)b * N_ + n0 + r) * C_ + tx] = f2bf(tile[tx][r]);
  }
}

// ---- furthest point sampling: 1 block/batch, 1 barrier/iter ----
// Exact semantics: d = ((dx*dx+dy*dy)+dz*dz) rn ops, min-update, argmax with
// first-index tie-break. Per-thread (bv,bj) tracking (strict > keeps first);
// u64 key = (valuebits<<32)|(8191-idx); key-only wave butterfly; cross-wave
// via one LDS atomicMax per wave (3-slot rotation, race-free); centroid via
// broadcast global reload (L1/L2-warm, same address across lanes).
__global__ __launch_bounds__(512) void fps_kernel(const float* __restrict__ xyz,
                                                  float* __restrict__ newxyz){
  const int b = blockIdx.x, t = threadIdx.x;
  const float* px = xyz + (size_t)b * N_ * 3;
  float X[16], Y[16], Z[16], MD[16];
#pragma unroll
  for (int j = 0; j < 16; j++){
    int p = j * 512 + t;
    X[j] = px[3 * p]; Y[j] = px[3 * p + 1]; Z[j] = px[3 * p + 2];
    MD[j] = 1e10f;
  }
  __shared__ unsigned long long slot[3];
  if (t == 0){
    slot[0] = 0ull; slot[1] = 0ull; slot[2] = 0ull;
    size_t o = (size_t)b * S_ * 3;
    newxyz[o] = px[0]; newxyz[o + 1] = px[1]; newxyz[o + 2] = px[2];
  }
  float cx = px[0], cy = px[1], cz = px[2];
  __syncthreads();
  int cur = 1;                       // slot index = i % 3
  const unsigned lobase = 8191u - (unsigned)t;
  for (int i = 1; i < S_; i++){
    float bv = -1.f; int bj = 0;
#pragma unroll
    for (int j = 0; j < 16; j++){
      float dx = __fsub_rn(X[j], cx);
      float dy = __fsub_rn(Y[j], cy);
      float dz = __fsub_rn(Z[j], cz);
      float d  = __fadd_rn(__fadd_rn(__fmul_rn(dx, dx), __fmul_rn(dy, dy)), __fmul_rn(dz, dz));
      float m  = fminf(MD[j], d);
      MD[j] = m;
      if (m > bv){ bv = m; bj = j; }   // ascending j: keeps first (smallest idx)
    }
    // bv >= 0 so float bits are order-preserving as uint; low field breaks
    // value ties toward the smaller global index.
    unsigned long long key = ((unsigned long long)__float_as_uint(bv) << 32)
                           | (unsigned long long)(lobase - (unsigned)(bj << 9));
#pragma unroll
    for (int off = 1; off < 64; off <<= 1){
      unsigned long long ok = __shfl_xor(key, off);
      if (ok > key) key = ok;
    }
    if ((t & 63) == 0) atomicMax(&slot[cur], key);          // 1 atomic per wave
    const int nxt = (cur == 2) ? 0 : cur + 1;
    if (t == 0) slot[nxt] = 0ull;   // zeroed pre-barrier; used post-barrier next iter
    __syncthreads();
    const unsigned long long g = slot[cur];
    const int fi = 8191 - (int)(g & 0xffffu);
    cx = px[3 * fi]; cy = px[3 * fi + 1]; cz = px[3 * fi + 2];  // broadcast load
    if (t == 0){
      size_t o = ((size_t)b * S_ + i) * 3;
      newxyz[o] = cx; newxyz[o + 1] = cy; newxyz[o + 2] = cz;
    }
    cur = nxt;
  }
}

// ---- ball query: 1 wave per centroid ----
__global__ __launch_bounds__(256) void ballq_kernel(const float* __restrict__ xyz,
                                                    const float* __restrict__ newxyz,
                                                    int* __restrict__ idxout){
  const int wave = threadIdx.x >> 6, lane = threadIdx.x & 63;
  const int cid = blockIdx.x * 4 + wave;
  const int b = cid >> 10;
  const float cx = newxyz[(size_t)cid * 3];
  const float cy = newxyz[(size_t)cid * 3 + 1];
  const float cz = newxyz[(size_t)cid * 3 + 2];
  const float* px = xyz + (size_t)b * N_ * 3;
  __shared__ int buf[4][32];
  const float r2 = 0.04f;   // fp32(double(0.2*0.2)) == 0x3D23D70A
  int have = 0;
  for (int base = 0; base < N_ && have < 32; base += 64){
    int p = base + lane;
    float dx = __fsub_rn(cx, px[3 * p]);
    float dy = __fsub_rn(cy, px[3 * p + 1]);
    float dz = __fsub_rn(cz, px[3 * p + 2]);
    float sq = __fadd_rn(__fadd_rn(__fmul_rn(dx, dx), __fmul_rn(dy, dy)), __fmul_rn(dz, dz));
    bool pred = sq < r2;
    unsigned long long m = __ballot(pred);
    if (pred){
      int pos = have + __popcll(m & ((1ull << lane) - 1ull));
      if (pos < 32) buf[wave][pos] = p;
    }
    have += (int)__popcll(m);
  }
  __syncthreads();
  if (lane < 32){
    int first = buf[wave][0];
    int v = (lane < have) ? buf[wave][lane] : first;
    idxout[(size_t)cid * 32 + lane] = v;
  }
}

// ---- LDS arena layout for the recompute pass kernels ----
template<int DEPTH>
struct PassLds {
  static constexpr int XS  = 0;                 // [32][36] f32 (x tile, col35 zeroed)
  static constexpr int W1O = XS + 32 * 36;      // [64][36] f32 (col35 zeroed)
  static constexpr int HA  = W1O + 64 * 36;     // [32][68] f32 (DEPTH>=2)
  static constexpr int W2O = HA + 32 * 68;      // [64][64] f32
  static constexpr int HB  = W2O + 64 * 64;     // [32][68] f32 (DEPTH==3)
  static constexpr int W3O = HB + 32 * 68;      // [128][64] bf16 -> 4096 f32 slots
  static constexpr int FLOATS = (DEPTH == 1) ? (W1O + 64 * 36)
                             : (DEPTH == 2) ? (W2O + 64 * 64)
                             : (W3O + 4096);    // D3: 16000 floats = 64000 B
};

// ---- fused recompute pass (512 threads: row = t&31, grp = t>>5 in [0,16)) ----
template<int DEPTH, bool FT>
__global__ __launch_bounds__(512) void pass_kernel(
    const float* __restrict__ xyz, const float* __restrict__ feat,
    const unsigned short* __restrict__ featT, const float* __restrict__ newxyz,
    const int* __restrict__ idx,
    const float* __restrict__ W1, const float* __restrict__ W2,
    const float* __restrict__ W3,
    const float* __restrict__ sab1, const float* __restrict__ sab2,
    float* __restrict__ partials,
    unsigned short* __restrict__ m3max, unsigned short* __restrict__ m3min){
  using L = PassLds<DEPTH>;
  __shared__ float sm[L::FLOATS];
  const int t = threadIdx.x;
  const int row = t & 31, grp = t >> 5;   // sample-row, channel-group

  // ---- stage weights once per block ----
  for (int i = t; i < 64 * 36; i += 512){
    int o = i / 36, c = i - o * 36;
    sm[L::W1O + i] = (c < 35) ? W1[o * 35 + c] : 0.f;
  }
  if constexpr (DEPTH >= 2){
    for (int i = t; i < 64 * 64; i += 512) sm[L::W2O + i] = W2[i];
  }
  unsigned short* w3p = nullptr;
  if constexpr (DEPTH == 3){
    w3p = (unsigned short*)&sm[L::W3O];
    for (int i = t; i < 128 * 64; i += 512) w3p[i] = f2bf(W3[i]);
  }

  // ---- per-thread BN params ----
  float sa1[4], sb1[4], sa2[4], sb2[4];
  if constexpr (DEPTH >= 2){
#pragma unroll
    for (int u = 0; u < 4; u++){ sa1[u] = sab1[grp * 4 + u]; sb1[u] = sab1[64 + grp * 4 + u]; }
  }
  if constexpr (DEPTH == 3){
#pragma unroll
    for (int u = 0; u < 4; u++){ sa2[u] = sab2[grp * 4 + u]; sb2[u] = sab2[64 + grp * 4 + u]; }
  }

  constexpr int US = (DEPTH == 3) ? 8 : 4;     // stats channels per thread
  float stS[US], stQ[US];
#pragma unroll
  for (int u = 0; u < US; u++){ stS[u] = 0.f; stQ[u] = 0.f; }

  for (int it = 0; it < 32; ++it){
    const int g = blockIdx.x * 32 + it;
    const int b = g >> 10;
    if constexpr (DEPTH == 1) __syncthreads();  // protect XS from prev readers

    // ---- gather x tile: [32 pts][3 rel-coords | 32 feats | 0 pad] ----
    {
      float* xr = &sm[L::XS + row * 36];
      if constexpr (FT){
        if (grp < 4){
          const int id = idx[(size_t)g * 32 + row];
          const uint4 f = *(const uint4*)(featT + ((size_t)b * N_ + id) * C_ + grp * 8);
          xr[3 + grp * 8 + 0] = bflo(f.x); xr[3 + grp * 8 + 1] = bfhi(f.x);
          xr[3 + grp * 8 + 2] = bflo(f.y); xr[3 + grp * 8 + 3] = bfhi(f.y);
          xr[3 + grp * 8 + 4] = bflo(f.z); xr[3 + grp * 8 + 5] = bfhi(f.z);
          xr[3 + grp * 8 + 6] = bflo(f.w); xr[3 + grp * 8 + 7] = bfhi(f.w);
        } else if (grp == 4){
          const int id = idx[(size_t)g * 32 + row];
          size_t pb = ((size_t)b * N_ + id) * 3;
          xr[0] = __fsub_rn(xyz[pb + 0], newxyz[(size_t)g * 3 + 0]);
          xr[1] = __fsub_rn(xyz[pb + 1], newxyz[(size_t)g * 3 + 1]);
          xr[2] = __fsub_rn(xyz[pb + 2], newxyz[(size_t)g * 3 + 2]);
          xr[35] = 0.f;
        }
      } else {
        if (grp < 8){
          const int id = idx[(size_t)g * 32 + row];
#pragma unroll
          for (int q = 0; q < 4; q++)
            xr[3 + grp * 4 + q] = feat[((size_t)b * C_ + grp * 4 + q) * N_ + id];
        } else if (grp == 8){
          const int id = idx[(size_t)g * 32 + row];
          size_t pb = ((size_t)b * N_ + id) * 3;
          xr[0] = __fsub_rn(xyz[pb + 0], newxyz[(size_t)g * 3 + 0]);
          xr[1] = __fsub_rn(xyz[pb + 1], newxyz[(size_t)g * 3 + 1]);
          xr[2] = __fsub_rn(xyz[pb + 2], newxyz[(size_t)g * 3 + 2]);
          xr[35] = 0.f;
        }
      }
    }
    __syncthreads();

    // ---- mm1: y1[row][grp*4+u] ----
    float acc[4] = {0.f, 0.f, 0.f, 0.f};
#pragma unroll 3
    for (int cb = 0; cb < 36; cb += 4){
      const float4 xv = *(const float4*)&sm[L::XS + row * 36 + cb];
#pragma unroll
      for (int u = 0; u < 4; u++){
        const float4 wv = *(const float4*)&sm[L::W1O + (grp * 4 + u) * 36 + cb];
        acc[u] = fmaf(xv.x, wv.x, acc[u]);
        acc[u] = fmaf(xv.y, wv.y, acc[u]);
        acc[u] = fmaf(xv.z, wv.z, acc[u]);
        acc[u] = fmaf(xv.w, wv.w, acc[u]);
      }
    }
    if constexpr (DEPTH == 1){
#pragma unroll
      for (int u = 0; u < 4; u++){ stS[u] += acc[u]; stQ[u] = fmaf(acc[u], acc[u], stQ[u]); }
      continue;
    }

    if constexpr (DEPTH >= 2){
      // ---- bn1 + relu -> hA ----
#pragma unroll
      for (int u = 0; u < 4; u++)
        sm[L::HA + row * 68 + grp * 4 + u] = fmaxf(fmaf(acc[u], sa1[u], sb1[u]), 0.f);
      __syncthreads();

      // ---- mm2 ----
      float acc2[4] = {0.f, 0.f, 0.f, 0.f};
#pragma unroll 4
      for (int cb = 0; cb < 64; cb += 4){
        const float4 xv = *(const float4*)&sm[L::HA + row * 68 + cb];
#pragma unroll
        for (int u = 0; u < 4; u++){
          const float4 wv = *(const float4*)&sm[L::W2O + (grp * 4 + u) * 64 + cb];
          acc2[u] = fmaf(xv.x, wv.x, acc2[u]);
          acc2[u] = fmaf(xv.y, wv.y, acc2[u]);
          acc2[u] = fmaf(xv.z, wv.z, acc2[u]);
          acc2[u] = fmaf(xv.w, wv.w, acc2[u]);
        }
      }
      if constexpr (DEPTH == 2){
#pragma unroll
        for (int u = 0; u < 4; u++){ stS[u] += acc2[u]; stQ[u] = fmaf(acc2[u], acc2[u], stQ[u]); }
        continue;
      }

      if constexpr (DEPTH == 3){
        // ---- bn2 + relu -> hB ----
#pragma unroll
        for (int u = 0; u < 4; u++)
          sm[L::HB + row * 68 + grp * 4 + u] = fmaxf(fmaf(acc2[u], sa2[u], sb2[u]), 0.f);
        __syncthreads();

        // ---- mm3: y3[row][grp*8+u], W3 bf16 in LDS ----
        float acc3[8];
#pragma unroll
        for (int u = 0; u < 8; u++) acc3[u] = 0.f;
#pragma unroll 2
        for (int cb = 0; cb < 64; cb += 4){
          const float4 xv = *(const float4*)&sm[L::HB + row * 68 + cb];
#pragma unroll
          for (int u = 0; u < 8; u++){
            const uint2 wp = *(const uint2*)&w3p[(grp * 8 + u) * 64 + cb];
            acc3[u] = fmaf(xv.x, bflo(wp.x), acc3[u]);
            acc3[u] = fmaf(xv.y, bfhi(wp.x), acc3[u]);
            acc3[u] = fmaf(xv.z, bflo(wp.y), acc3[u]);
            acc3[u] = fmaf(xv.w, bfhi(wp.y), acc3[u]);
          }
        }
#pragma unroll
        for (int u = 0; u < 8; u++){ stS[u] += acc3[u]; stQ[u] = fmaf(acc3[u], acc3[u], stQ[u]); }

        // ---- pre-BN max/min over the 32 rows (lanes within half-wave) ----
        const int s = g & 1023;
#pragma unroll
        for (int u = 0; u < 8; u++){
          float mx = acc3[u], mn = acc3[u];
#pragma unroll
          for (int m = 1; m < 32; m <<= 1){
            mx = fmaxf(mx, __shfl_xor(mx, m));
            mn = fminf(mn, __shfl_xor(mn, m));
          }
          if (row == 0){
            size_t o = ((size_t)b * 128 + grp * 8 + u) * 1024 + s;
            m3max[o] = f2bf(mx); m3min[o] = f2bf(mn);
          }
        }
      }
    }
  }

  // ---- block stats partials: reduce over rows (half-wave lanes) ----
#pragma unroll
  for (int m = 1; m < 32; m <<= 1){
#pragma unroll
    for (int u = 0; u < US; u++){
      stS[u] += __shfl_xor(stS[u], m);
      stQ[u] += __shfl_xor(stQ[u], m);
    }
  }
  if (row == 0){
    constexpr int CH = (DEPTH == 3) ? 128 : 64;
    float* p = partials + (size_t)blockIdx.x * (2 * CH);
    const int o0 = grp * US;
#pragma unroll
    for (int u = 0; u < US; u++){ p[o0 + u] = stS[u]; p[CH + o0 + u] = stQ[u]; }
  }
}

// ---- stats stage 2: reduce 512 partial rows, emit per-channel scale/shift ----
template<int CH>
__global__ __launch_bounds__(256) void stats_fin(const float* __restrict__ partials,
                                                 const float* __restrict__ g,
                                                 const float* __restrict__ bet,
                                                 float* __restrict__ sab){
  const int t = threadIdx.x;
  __shared__ float red[2 * CH];
  if (t < 2 * CH){
    float a = 0.f;
#pragma unroll 8
    for (int r = 0; r < 512; r++) a += partials[(size_t)r * (2 * CH) + t];
    red[t] = a;
  }
  __syncthreads();
  if (t < CH){
    constexpr float inv = 1.f / (float)((size_t)B_ * S_ * K_);
    float mean = red[t] * inv;
    float var  = red[CH + t] * inv - mean * mean;
    float r    = 1.f / sqrtf(var + BN_EPS_);
    float a    = r * g[t];
    sab[t] = a;
    sab[CH + t] = bet[t] - mean * a;
  }
}

// ---- final: bn3(+relu) on bf16 pre-BN max/min (monotone-affine dispatch) ----
__global__ __launch_bounds__(256) void final_kernel(const unsigned short* __restrict__ m3max,
                                                    const unsigned short* __restrict__ m3min,
                                                    const float* __restrict__ sab3,
                                                    float* __restrict__ outNF){
  const int q = blockIdx.x * 256 + threadIdx.x;   // quad index over B*128*1024/4
  const int e = q * 4;
  const int o = (e >> 10) & 127;
  const float a = sab3[o], c = sab3[128 + o];
  const ushort4 mx = ((const ushort4*)m3max)[q];
  const ushort4 mn = ((const ushort4*)m3min)[q];
  float4 r;
  r.x = fmaxf(fmaf(bfu(a >= 0.f ? mx.x : mn.x), a, c), 0.f);
  r.y = fmaxf(fmaf(bfu(a >= 0.f ? mx.y : mn.y), a, c), 0.f);
  r.z = fmaxf(fmaf(bfu(a >= 0.f ? mx.z : mn.z), a, c), 0.f);
  r.w = fmaxf(fmaf(bfu(a >= 0.f ? mx.w : mn.w), a, c), 0.f);
  ((float4*)outNF)[q] = r;
}

extern "C" void kernel_launch(void* const* d_in, const int* in_sizes, int n_in,
                              void* d_out, int out_size, void* d_ws, size_t ws_size,
                              hipStream_t stream){
  (void)in_sizes; (void)n_in; (void)out_size;
  const float* xyz = (const float*)d_in[0];
  const float* feat = (const float*)d_in[1];
  const float* W1 = (const float*)d_in[2];
  const float* g1 = (const float*)d_in[3];
  const float* b1 = (const float*)d_in[4];
  const float* W2 = (const float*)d_in[5];
  const float* g2 = (const float*)d_in[6];
  const float* b2 = (const float*)d_in[7];
  const float* W3 = (const float*)d_in[8];
  const float* g3 = (const float*)d_in[9];
  const float* b3 = (const float*)d_in[10];

  float* newxyz = (float*)d_out;                       // (B,S,3)
  float* outNF  = newxyz + (size_t)B_ * S_ * 3;        // (B,128,S)
  char* ws = (char*)d_ws;

  size_t off = 0;
  auto alloc = [&](size_t bytes){ size_t o = off; off += (bytes + 255) & ~(size_t)255; return o; };
  size_t o_idx  = alloc((size_t)B_ * S_ * K_ * 4);           // 2 MB
  size_t o_part = alloc((size_t)512 * 256 * 4);              // 512 KB
  size_t o_sab1 = alloc(1024);
  size_t o_sab2 = alloc(1024);
  size_t o_sab3 = alloc(1024);
  size_t o_m3mx = alloc((size_t)B_ * S_ * 128 * 2);          // 4 MB (bf16)
  size_t o_m3mn = alloc((size_t)B_ * S_ * 128 * 2);          // 4 MB (bf16)
  size_t o_featT = alloc((size_t)B_ * N_ * C_ * 2);          // 8 MB (bf16)
  const bool ft = ws_size >= off;                            // 19.4 MB total

  int*   idxp  = (int*)(ws + o_idx);
  float* part  = (float*)(ws + o_part);
  float* sab1  = (float*)(ws + o_sab1);
  float* sab2  = (float*)(ws + o_sab2);
  float* sab3  = (float*)(ws + o_sab3);
  unsigned short* m3mx  = (unsigned short*)(ws + o_m3mx);
  unsigned short* m3mn  = (unsigned short*)(ws + o_m3mn);
  unsigned short* featT = (unsigned short*)(ws + o_featT);

  if (ft) transpose_kernel<<<dim3(N_ / 32, B_), dim3(32, 8), 0, stream>>>(feat, featT);
  fps_kernel<<<B_, 512, 0, stream>>>(xyz, newxyz);
  ballq_kernel<<<B_ * S_ / 4, 256, 0, stream>>>(xyz, newxyz, idxp);

  if (ft){
    pass_kernel<1, true><<<512, 512, 0, stream>>>(xyz, feat, featT, newxyz, idxp,
        W1, W2, W3, sab1, sab2, part, m3mx, m3mn);
    stats_fin<64><<<1, 256, 0, stream>>>(part, g1, b1, sab1);
    pass_kernel<2, true><<<512, 512, 0, stream>>>(xyz, feat, featT, newxyz, idxp,
        W1, W2, W3, sab1, sab2, part, m3mx, m3mn);
    stats_fin<64><<<1, 256, 0, stream>>>(part, g2, b2, sab2);
    pass_kernel<3, true><<<512, 512, 0, stream>>>(xyz, feat, featT, newxyz, idxp,
        W1, W2, W3, sab1, sab2, part, m3mx, m3mn);
    stats_fin<128><<<1, 256, 0, stream>>>(part, g3, b3, sab3);
  } else {
    pass_kernel<1, false><<<512, 512, 0, stream>>>(xyz, feat, featT, newxyz, idxp,
        W1, W2, W3, sab1, sab2, part, m3mx, m3mn);
    stats_fin<64><<<1, 256, 0, stream>>>(part, g1, b1, sab1);
    pass_kernel<2, false><<<512, 512, 0, stream>>>(xyz, feat, featT, newxyz, idxp,
        W1, W2, W3, sab1, sab2, part, m3mx, m3mn);
    stats_fin<64><<<1, 256, 0, stream>>>(part, g2, b2, sab2);
    pass_kernel<3, false><<<512, 512, 0, stream>>>(xyz, feat, featT, newxyz, idxp,
        W1, W2, W3, sab1, sab2, part, m3mx, m3mn);
    stats_fin<128><<<1, 256, 0, stream>>>(part, g3, b3, sab3);
  }
  final_kernel<<<(B_ * 128 * S_) / 1024, 256, 0, stream>>>(m3mx, m3mn, sab3, outNF);
}

// Round 6
// 1999.049 us; speedup vs baseline: 2.1473x; 1.0335x over previous
//
#include <hip/hip_runtime.h>
#include <hip/hip_bf16.h>

// ---- problem constants ----
static constexpr int B_ = 16;
static constexpr int N_ = 8192;
static constexpr int C_ = 32;     // input feature channels
static constexpr int S_ = 1024;   // NPOINT
static constexpr int K_ = 32;     // NSAMPLE
static constexpr float BN_EPS_ = 1e-5f;

__device__ __forceinline__ unsigned short f2bf(float f){
  unsigned u = __float_as_uint(f);
  unsigned r = (u + 0x7fffu + ((u >> 16) & 1u)) >> 16;
  return (unsigned short)r;
}
__device__ __forceinline__ float bflo(unsigned u){ return __int_as_float(u << 16); }
__device__ __forceinline__ float bfhi(unsigned u){ return __int_as_float(u & 0xffff0000u); }
__device__ __forceinline__ float bfu(unsigned short u){ return __int_as_float(((unsigned)u) << 16); }

// ---- features (B,C,N) f32 -> featT (B,N,C) bf16 ----
__global__ __launch_bounds__(256) void transpose_kernel(const float* __restrict__ feat,
                                                        unsigned short* __restrict__ featT){
  __shared__ float tile[32][33];
  const int b = blockIdx.y;
  const int n0 = blockIdx.x * 32;
  const int tx = threadIdx.x, ty = threadIdx.y;
#pragma unroll
  for (int i = 0; i < 4; i++){
    int c = ty + i * 8;
    tile[c][tx] = feat[((size_t)b * C_ + c) * N_ + n0 + tx];
  }
  __syncthreads();
#pragma unroll
  for (int i = 0; i < 4; i++){
    int r = ty + i * 8;
    featT[((size_t)b * N_ + n0 + r) * C_ + tx] = f2bf(tile[tx][r]);
  }
}

// ---- furthest point sampling: 1 block/batch, 1 barrier/iter ----
// Exact semantics: d = ((dx*dx+dy*dy)+dz*dz) rn ops, min-update, argmax with
// first-index tie-break. X/Y/Z pinned in VGPRs via opaque asm (prevents the
// compiler rematerializing them as per-iteration global reloads). Centroid
// fetched from an LDS-resident copy of the batch's points (broadcast ds_read)
// instead of a dependent global load on the serial critical path.
__global__ __launch_bounds__(512) void fps_kernel(const float* __restrict__ xyz,
                                                  float* __restrict__ newxyz){
  const int b = blockIdx.x, t = threadIdx.x;
  const float* px = xyz + (size_t)b * N_ * 3;
  __shared__ float pl[N_ * 3];                    // 96 KB AoS copy of the batch
  __shared__ unsigned long long slot[3];

  // coalesced global -> LDS copy (float4, 12 per thread)
  for (int i = t; i < N_ * 3 / 4; i += 512)
    ((float4*)pl)[i] = ((const float4*)px)[i];

  float X[16], Y[16], Z[16], MD[16];
#pragma unroll
  for (int j = 0; j < 16; j++){
    int p = j * 512 + t;
    X[j] = px[3 * p]; Y[j] = px[3 * p + 1]; Z[j] = px[3 * p + 2];
    MD[j] = 1e10f;
    asm volatile("" : "+v"(X[j]), "+v"(Y[j]), "+v"(Z[j]));   // pin in VGPRs
  }
  if (t == 0){
    slot[0] = 0ull; slot[1] = 0ull; slot[2] = 0ull;
    size_t o = (size_t)b * S_ * 3;
    newxyz[o] = px[0]; newxyz[o + 1] = px[1]; newxyz[o + 2] = px[2];
  }
  float cx = px[0], cy = px[1], cz = px[2];
  __syncthreads();                                // covers pl copy + slot init
  int cur = 1;                                    // slot index = i % 3
  const unsigned lobase = 8191u - (unsigned)t;
  for (int i = 1; i < S_; i++){
    float bv = -1.f; int bj = 0;
#pragma unroll
    for (int j = 0; j < 16; j++){
      float dx = __fsub_rn(X[j], cx);
      float dy = __fsub_rn(Y[j], cy);
      float dz = __fsub_rn(Z[j], cz);
      float d  = __fadd_rn(__fadd_rn(__fmul_rn(dx, dx), __fmul_rn(dy, dy)), __fmul_rn(dz, dz));
      float m  = fminf(MD[j], d);
      MD[j] = m;
      if (m > bv){ bv = m; bj = j; }   // ascending j: keeps first (smallest idx)
    }
    // bv >= 0 so float bits are order-preserving as uint; low field breaks
    // value ties toward the smaller global index.
    unsigned long long key = ((unsigned long long)__float_as_uint(bv) << 32)
                           | (unsigned long long)(lobase - (unsigned)(bj << 9));
#pragma unroll
    for (int off = 1; off < 64; off <<= 1){
      unsigned long long ok = __shfl_xor(key, off);
      if (ok > key) key = ok;
    }
    if ((t & 63) == 0) atomicMax(&slot[cur], key);          // 1 atomic per wave
    const int nxt = (cur == 2) ? 0 : cur + 1;
    if (t == 0) slot[nxt] = 0ull;   // zeroed pre-barrier; used post-barrier next iter
    __syncthreads();
    const unsigned long long g = slot[cur];
    const int fi = 8191 - (int)(g & 0xffffu);
    cx = pl[3 * fi]; cy = pl[3 * fi + 1]; cz = pl[3 * fi + 2];  // LDS broadcast
    if (t == 0){
      size_t o = ((size_t)b * S_ + i) * 3;
      newxyz[o] = cx; newxyz[o + 1] = cy; newxyz[o + 2] = cz;
    }
    cur = nxt;
  }
}

// ---- ball query: 1 wave per centroid ----
__global__ __launch_bounds__(256) void ballq_kernel(const float* __restrict__ xyz,
                                                    const float* __restrict__ newxyz,
                                                    int* __restrict__ idxout){
  const int wave = threadIdx.x >> 6, lane = threadIdx.x & 63;
  const int cid = blockIdx.x * 4 + wave;
  const int b = cid >> 10;
  const float cx = newxyz[(size_t)cid * 3];
  const float cy = newxyz[(size_t)cid * 3 + 1];
  const float cz = newxyz[(size_t)cid * 3 + 2];
  const float* px = xyz + (size_t)b * N_ * 3;
  __shared__ int buf[4][32];
  const float r2 = 0.04f;   // fp32(double(0.2*0.2)) == 0x3D23D70A
  int have = 0;
  for (int base = 0; base < N_ && have < 32; base += 64){
    int p = base + lane;
    float dx = __fsub_rn(cx, px[3 * p]);
    float dy = __fsub_rn(cy, px[3 * p + 1]);
    float dz = __fsub_rn(cz, px[3 * p + 2]);
    float sq = __fadd_rn(__fadd_rn(__fmul_rn(dx, dx), __fmul_rn(dy, dy)), __fmul_rn(dz, dz));
    bool pred = sq < r2;
    unsigned long long m = __ballot(pred);
    if (pred){
      int pos = have + __popcll(m & ((1ull << lane) - 1ull));
      if (pos < 32) buf[wave][pos] = p;
    }
    have += (int)__popcll(m);
  }
  __syncthreads();
  if (lane < 32){
    int first = buf[wave][0];
    int v = (lane < have) ? buf[wave][lane] : first;
    idxout[(size_t)cid * 32 + lane] = v;
  }
}

// ---- LDS arena layout for the recompute pass kernels ----
template<int DEPTH>
struct PassLds {
  static constexpr int XS  = 0;                 // [32][36] f32 (x tile, col35 zeroed)
  static constexpr int W1O = XS + 32 * 36;      // [64][36] f32 (col35 zeroed)
  static constexpr int HA  = W1O + 64 * 36;     // [32][68] f32 (DEPTH>=2)
  static constexpr int W2O = HA + 32 * 68;      // [64][64] f32
  static constexpr int HB  = W2O + 64 * 64;     // [32][68] f32 (DEPTH==3)
  static constexpr int W3O = HB + 32 * 68;      // [128][64] bf16 -> 4096 f32 slots
  static constexpr int FLOATS = (DEPTH == 1) ? (W1O + 64 * 36)
                             : (DEPTH == 2) ? (W2O + 64 * 64)
                             : (W3O + 4096);    // D3: 16000 floats = 64000 B
};

// ---- fused recompute pass (512 threads: row = t&31, grp = t>>5 in [0,16)) ----
template<int DEPTH, bool FT>
__global__ __launch_bounds__(512) void pass_kernel(
    const float* __restrict__ xyz, const float* __restrict__ feat,
    const unsigned short* __restrict__ featT, const float* __restrict__ newxyz,
    const int* __restrict__ idx,
    const float* __restrict__ W1, const float* __restrict__ W2,
    const float* __restrict__ W3,
    const float* __restrict__ sab1, const float* __restrict__ sab2,
    float* __restrict__ partials,
    unsigned short* __restrict__ m3max, unsigned short* __restrict__ m3min){
  using L = PassLds<DEPTH>;
  __shared__ float sm[L::FLOATS];
  const int t = threadIdx.x;
  const int row = t & 31, grp = t >> 5;   // sample-row, channel-group

  // ---- stage weights once per block ----
  for (int i = t; i < 64 * 36; i += 512){
    int o = i / 36, c = i - o * 36;
    sm[L::W1O + i] = (c < 35) ? W1[o * 35 + c] : 0.f;
  }
  if constexpr (DEPTH >= 2){
    for (int i = t; i < 64 * 64; i += 512) sm[L::W2O + i] = W2[i];
  }
  unsigned short* w3p = nullptr;
  if constexpr (DEPTH == 3){
    w3p = (unsigned short*)&sm[L::W3O];
    for (int i = t; i < 128 * 64; i += 512) w3p[i] = f2bf(W3[i]);
  }

  // ---- per-thread BN params ----
  float sa1[4], sb1[4], sa2[4], sb2[4];
  if constexpr (DEPTH >= 2){
#pragma unroll
    for (int u = 0; u < 4; u++){ sa1[u] = sab1[grp * 4 + u]; sb1[u] = sab1[64 + grp * 4 + u]; }
  }
  if constexpr (DEPTH == 3){
#pragma unroll
    for (int u = 0; u < 4; u++){ sa2[u] = sab2[grp * 4 + u]; sb2[u] = sab2[64 + grp * 4 + u]; }
  }

  constexpr int US = (DEPTH == 3) ? 8 : 4;     // stats channels per thread
  float stS[US], stQ[US];
#pragma unroll
  for (int u = 0; u < US; u++){ stS[u] = 0.f; stQ[u] = 0.f; }

  for (int it = 0; it < 32; ++it){
    const int g = blockIdx.x * 32 + it;
    const int b = g >> 10;
    if constexpr (DEPTH == 1) __syncthreads();  // protect XS from prev readers

    // ---- gather x tile: [32 pts][3 rel-coords | 32 feats | 0 pad] ----
    {
      float* xr = &sm[L::XS + row * 36];
      if constexpr (FT){
        if (grp < 4){
          const int id = idx[(size_t)g * 32 + row];
          const uint4 f = *(const uint4*)(featT + ((size_t)b * N_ + id) * C_ + grp * 8);
          xr[3 + grp * 8 + 0] = bflo(f.x); xr[3 + grp * 8 + 1] = bfhi(f.x);
          xr[3 + grp * 8 + 2] = bflo(f.y); xr[3 + grp * 8 + 3] = bfhi(f.y);
          xr[3 + grp * 8 + 4] = bflo(f.z); xr[3 + grp * 8 + 5] = bfhi(f.z);
          xr[3 + grp * 8 + 6] = bflo(f.w); xr[3 + grp * 8 + 7] = bfhi(f.w);
        } else if (grp == 4){
          const int id = idx[(size_t)g * 32 + row];
          size_t pb = ((size_t)b * N_ + id) * 3;
          xr[0] = __fsub_rn(xyz[pb + 0], newxyz[(size_t)g * 3 + 0]);
          xr[1] = __fsub_rn(xyz[pb + 1], newxyz[(size_t)g * 3 + 1]);
          xr[2] = __fsub_rn(xyz[pb + 2], newxyz[(size_t)g * 3 + 2]);
          xr[35] = 0.f;
        }
      } else {
        if (grp < 8){
          const int id = idx[(size_t)g * 32 + row];
#pragma unroll
          for (int q = 0; q < 4; q++)
            xr[3 + grp * 4 + q] = feat[((size_t)b * C_ + grp * 4 + q) * N_ + id];
        } else if (grp == 8){
          const int id = idx[(size_t)g * 32 + row];
          size_t pb = ((size_t)b * N_ + id) * 3;
          xr[0] = __fsub_rn(xyz[pb + 0], newxyz[(size_t)g * 3 + 0]);
          xr[1] = __fsub_rn(xyz[pb + 1], newxyz[(size_t)g * 3 + 1]);
          xr[2] = __fsub_rn(xyz[pb + 2], newxyz[(size_t)g * 3 + 2]);
          xr[35] = 0.f;
        }
      }
    }
    __syncthreads();

    // ---- mm1: y1[row][grp*4+u] ----
    float acc[4] = {0.f, 0.f, 0.f, 0.f};
#pragma unroll 3
    for (int cb = 0; cb < 36; cb += 4){
      const float4 xv = *(const float4*)&sm[L::XS + row * 36 + cb];
#pragma unroll
      for (int u = 0; u < 4; u++){
        const float4 wv = *(const float4*)&sm[L::W1O + (grp * 4 + u) * 36 + cb];
        acc[u] = fmaf(xv.x, wv.x, acc[u]);
        acc[u] = fmaf(xv.y, wv.y, acc[u]);
        acc[u] = fmaf(xv.z, wv.z, acc[u]);
        acc[u] = fmaf(xv.w, wv.w, acc[u]);
      }
    }
    if constexpr (DEPTH == 1){
#pragma unroll
      for (int u = 0; u < 4; u++){ stS[u] += acc[u]; stQ[u] = fmaf(acc[u], acc[u], stQ[u]); }
      continue;
    }

    if constexpr (DEPTH >= 2){
      // ---- bn1 + relu -> hA ----
#pragma unroll
      for (int u = 0; u < 4; u++)
        sm[L::HA + row * 68 + grp * 4 + u] = fmaxf(fmaf(acc[u], sa1[u], sb1[u]), 0.f);
      __syncthreads();

      // ---- mm2 ----
      float acc2[4] = {0.f, 0.f, 0.f, 0.f};
#pragma unroll 4
      for (int cb = 0; cb < 64; cb += 4){
        const float4 xv = *(const float4*)&sm[L::HA + row * 68 + cb];
#pragma unroll
        for (int u = 0; u < 4; u++){
          const float4 wv = *(const float4*)&sm[L::W2O + (grp * 4 + u) * 64 + cb];
          acc2[u] = fmaf(xv.x, wv.x, acc2[u]);
          acc2[u] = fmaf(xv.y, wv.y, acc2[u]);
          acc2[u] = fmaf(xv.z, wv.z, acc2[u]);
          acc2[u] = fmaf(xv.w, wv.w, acc2[u]);
        }
      }
      if constexpr (DEPTH == 2){
#pragma unroll
        for (int u = 0; u < 4; u++){ stS[u] += acc2[u]; stQ[u] = fmaf(acc2[u], acc2[u], stQ[u]); }
        continue;
      }

      if constexpr (DEPTH == 3){
        // ---- bn2 + relu -> hB ----
#pragma unroll
        for (int u = 0; u < 4; u++)
          sm[L::HB + row * 68 + grp * 4 + u] = fmaxf(fmaf(acc2[u], sa2[u], sb2[u]), 0.f);
        __syncthreads();

        // ---- mm3: y3[row][grp*8+u], W3 bf16 in LDS ----
        float acc3[8];
#pragma unroll
        for (int u = 0; u < 8; u++) acc3[u] = 0.f;
#pragma unroll 2
        for (int cb = 0; cb < 64; cb += 4){
          const float4 xv = *(const float4*)&sm[L::HB + row * 68 + cb];
#pragma unroll
          for (int u = 0; u < 8; u++){
            const uint2 wp = *(const uint2*)&w3p[(grp * 8 + u) * 64 + cb];
            acc3[u] = fmaf(xv.x, bflo(wp.x), acc3[u]);
            acc3[u] = fmaf(xv.y, bfhi(wp.x), acc3[u]);
            acc3[u] = fmaf(xv.z, bflo(wp.y), acc3[u]);
            acc3[u] = fmaf(xv.w, bfhi(wp.y), acc3[u]);
          }
        }
#pragma unroll
        for (int u = 0; u < 8; u++){ stS[u] += acc3[u]; stQ[u] = fmaf(acc3[u], acc3[u], stQ[u]); }

        // ---- pre-BN max/min over the 32 rows (lanes within half-wave) ----
        const int s = g & 1023;
#pragma unroll
        for (int u = 0; u < 8; u++){
          float mx = acc3[u], mn = acc3[u];
#pragma unroll
          for (int m = 1; m < 32; m <<= 1){
            mx = fmaxf(mx, __shfl_xor(mx, m));
            mn = fminf(mn, __shfl_xor(mn, m));
          }
          if (row == 0){
            size_t o = ((size_t)b * 128 + grp * 8 + u) * 1024 + s;
            m3max[o] = f2bf(mx); m3min[o] = f2bf(mn);
          }
        }
      }
    }
  }

  // ---- block stats partials: reduce over rows (half-wave lanes) ----
#pragma unroll
  for (int m = 1; m < 32; m <<= 1){
#pragma unroll
    for (int u = 0; u < US; u++){
      stS[u] += __shfl_xor(stS[u], m);
      stQ[u] += __shfl_xor(stQ[u], m);
    }
  }
  if (row == 0){
    constexpr int CH = (DEPTH == 3) ? 128 : 64;
    float* p = partials + (size_t)blockIdx.x * (2 * CH);
    const int o0 = grp * US;
#pragma unroll
    for (int u = 0; u < US; u++){ p[o0 + u] = stS[u]; p[CH + o0 + u] = stQ[u]; }
  }
}

// ---- stats stage 2: reduce 512 partial rows, emit per-channel scale/shift ----
template<int CH>
__global__ __launch_bounds__(256) void stats_fin(const float* __restrict__ partials,
                                                 const float* __restrict__ g,
                                                 const float* __restrict__ bet,
                                                 float* __restrict__ sab){
  const int t = threadIdx.x;
  __shared__ float red[2 * CH];
  if (t < 2 * CH){
    float a = 0.f;
#pragma unroll 8
    for (int r = 0; r < 512; r++) a += partials[(size_t)r * (2 * CH) + t];
    red[t] = a;
  }
  __syncthreads();
  if (t < CH){
    constexpr float inv = 1.f / (float)((size_t)B_ * S_ * K_);
    float mean = red[t] * inv;
    float var  = red[CH + t] * inv - mean * mean;
    float r    = 1.f / sqrtf(var + BN_EPS_);
    float a    = r * g[t];
    sab[t] = a;
    sab[CH + t] = bet[t] - mean * a;
  }
}

// ---- final: bn3(+relu) on bf16 pre-BN max/min (monotone-affine dispatch) ----
__global__ __launch_bounds__(256) void final_kernel(const unsigned short* __restrict__ m3max,
                                                    const unsigned short* __restrict__ m3min,
                                                    const float* __restrict__ sab3,
                                                    float* __restrict__ outNF){
  const int q = blockIdx.x * 256 + threadIdx.x;   // quad index over B*128*1024/4
  const int e = q * 4;
  const int o = (e >> 10) & 127;
  const float a = sab3[o], c = sab3[128 + o];
  const ushort4 mx = ((const ushort4*)m3max)[q];
  const ushort4 mn = ((const ushort4*)m3min)[q];
  float4 r;
  r.x = fmaxf(fmaf(bfu(a >= 0.f ? mx.x : mn.x), a, c), 0.f);
  r.y = fmaxf(fmaf(bfu(a >= 0.f ? mx.y : mn.y), a, c), 0.f);
  r.z = fmaxf(fmaf(bfu(a >= 0.f ? mx.z : mn.z), a, c), 0.f);
  r.w = fmaxf(fmaf(bfu(a >= 0.f ? mx.w : mn.w), a, c), 0.f);
  ((float4*)outNF)[q] = r;
}

extern "C" void kernel_launch(void* const* d_in, const int* in_sizes, int n_in,
                              void* d_out, int out_size, void* d_ws, size_t ws_size,
                              hipStream_t stream){
  (void)in_sizes; (void)n_in; (void)out_size;
  const float* xyz = (const float*)d_in[0];
  const float* feat = (const float*)d_in[1];
  const float* W1 = (const float*)d_in[2];
  const float* g1 = (const float*)d_in[3];
  const float* b1 = (const float*)d_in[4];
  const float* W2 = (const float*)d_in[5];
  const float* g2 = (const float*)d_in[6];
  const float* b2 = (const float*)d_in[7];
  const float* W3 = (const float*)d_in[8];
  const float* g3 = (const float*)d_in[9];
  const float* b3 = (const float*)d_in[10];

  float* newxyz = (float*)d_out;                       // (B,S,3)
  float* outNF  = newxyz + (size_t)B_ * S_ * 3;        // (B,128,S)
  char* ws = (char*)d_ws;

  size_t off = 0;
  auto alloc = [&](size_t bytes){ size_t o = off; off += (bytes + 255) & ~(size_t)255; return o; };
  size_t o_idx  = alloc((size_t)B_ * S_ * K_ * 4);           // 2 MB
  size_t o_part = alloc((size_t)512 * 256 * 4);              // 512 KB
  size_t o_sab1 = alloc(1024);
  size_t o_sab2 = alloc(1024);
  size_t o_sab3 = alloc(1024);
  size_t o_m3mx = alloc((size_t)B_ * S_ * 128 * 2);          // 4 MB (bf16)
  size_t o_m3mn = alloc((size_t)B_ * S_ * 128 * 2);          // 4 MB (bf16)
  size_t o_featT = alloc((size_t)B_ * N_ * C_ * 2);          // 8 MB (bf16)
  const bool ft = ws_size >= off;                            // 19.4 MB total

  int*   idxp  = (int*)(ws + o_idx);
  float* part  = (float*)(ws + o_part);
  float* sab1  = (float*)(ws + o_sab1);
  float* sab2  = (float*)(ws + o_sab2);
  float* sab3  = (float*)(ws + o_sab3);
  unsigned short* m3mx  = (unsigned short*)(ws + o_m3mx);
  unsigned short* m3mn  = (unsigned short*)(ws + o_m3mn);
  unsigned short* featT = (unsigned short*)(ws + o_featT);

  if (ft) transpose_kernel<<<dim3(N_ / 32, B_), dim3(32, 8), 0, stream>>>(feat, featT);
  fps_kernel<<<B_, 512, 0, stream>>>(xyz, newxyz);
  ballq_kernel<<<B_ * S_ / 4, 256, 0, stream>>>(xyz, newxyz, idxp);

  if (ft){
    pass_kernel<1, true><<<512, 512, 0, stream>>>(xyz, feat, featT, newxyz, idxp,
        W1, W2, W3, sab1, sab2, part, m3mx, m3mn);
    stats_fin<64><<<1, 256, 0, stream>>>(part, g1, b1, sab1);
    pass_kernel<2, true><<<512, 512, 0, stream>>>(xyz, feat, featT, newxyz, idxp,
        W1, W2, W3, sab1, sab2, part, m3mx, m3mn);
    stats_fin<64><<<1, 256, 0, stream>>>(part, g2, b2, sab2);
    pass_kernel<3, true><<<512, 512, 0, stream>>>(xyz, feat, featT, newxyz, idxp,
        W1, W2, W3, sab1, sab2, part, m3mx, m3mn);
    stats_fin<128><<<1, 256, 0, stream>>>(part, g3, b3, sab3);
  } else {
    pass_kernel<1, false><<<512, 512, 0, stream>>>(xyz, feat, featT, newxyz, idxp,
        W1, W2, W3, sab1, sab2, part, m3mx, m3mn);
    stats_fin<64><<<1, 256, 0, stream>>>(part, g1, b1, sab1);
    pass_kernel<2, false><<<512, 512, 0, stream>>>(xyz, feat, featT, newxyz, idxp,
        W1, W2, W3, sab1, sab2, part, m3mx, m3mn);
    stats_fin<64><<<1, 256, 0, stream>>>(part, g2, b2, sab2);
    pass_kernel<3, false><<<512, 512, 0, stream>>>(xyz, feat, featT, newxyz, idxp,
        W1, W2, W3, sab1, sab2, part, m3mx, m3mn);
    stats_fin<128><<<1, 256, 0, stream>>>(part, g3, b3, sab3);
  }
  final_kernel<<<(B_ * 128 * S_) / 1024, 256, 0, stream>>>(m3mx, m3mn, sab3, outNF);
}

// Round 9
// 1794.835 us; speedup vs baseline: 2.3916x; 1.1138x over previous
//
#include <hip/hip_runtime.h>
#include <hip/hip_bf16.h>

// ---- problem constants ----
static constexpr int B_ = 16;
static constexpr int N_ = 8192;
static constexpr int C_ = 32;     // input feature channels
static constexpr int S_ = 1024;   // NPOINT
static constexpr int K_ = 32;     // NSAMPLE
static constexpr float BN_EPS_ = 1e-5f;

__device__ __forceinline__ unsigned short f2bf(float f){
  unsigned u = __float_as_uint(f);
  unsigned r = (u + 0x7fffu + ((u >> 16) & 1u)) >> 16;
  return (unsigned short)r;
}
__device__ __forceinline__ float bflo(unsigned u){ return __int_as_float(u << 16); }
__device__ __forceinline__ float bfhi(unsigned u){ return __int_as_float(u & 0xffff0000u); }
__device__ __forceinline__ float bfu(unsigned short u){ return __int_as_float(((unsigned)u) << 16); }

// rocPRIM-standard wave64 DPP reduce step on a u64 key. Both 32-bit halves
// move with the SAME lane permutation, so the u64 stays coherent. old=self +
// bound_ctrl=false: lanes with no valid source combine with their own value —
// idempotent under max.
template<int CTRL>
__device__ __forceinline__ unsigned long long dpp64(unsigned long long v){
  int lo = (int)(unsigned)(v & 0xffffffffull);
  int hi = (int)(unsigned)(v >> 32);
  int lo2 = __builtin_amdgcn_update_dpp(lo, lo, CTRL, 0xf, 0xf, false);
  int hi2 = __builtin_amdgcn_update_dpp(hi, hi, CTRL, 0xf, 0xf, false);
  return (((unsigned long long)(unsigned)hi2) << 32) | (unsigned)lo2;
}
__device__ __forceinline__ unsigned long long u64max(unsigned long long a,
                                                     unsigned long long b){
  return a > b ? a : b;
}

// ---- features (B,C,N) f32 -> featT (B,N,C) bf16 ----
__global__ __launch_bounds__(256) void transpose_kernel(const float* __restrict__ feat,
                                                        unsigned short* __restrict__ featT){
  __shared__ float tile[32][33];
  const int b = blockIdx.y;
  const int n0 = blockIdx.x * 32;
  const int tx = threadIdx.x, ty = threadIdx.y;
#pragma unroll
  for (int i = 0; i < 4; i++){
    int c = ty + i * 8;
    tile[c][tx] = feat[((size_t)b * C_ + c) * N_ + n0 + tx];
  }
  __syncthreads();
#pragma unroll
  for (int i = 0; i < 4; i++){
    int r = ty + i * 8;
    featT[((size_t)b * N_ + n0 + r) * C_ + tx] = f2bf(tile[tx][r]);
  }
}

// ---- furthest point sampling: 1 block/batch, 1 barrier/iter ----
// EXACT round-6 (HW-passing) skeleton: scalar X/Y/Z/MD with scalar asm pins,
// __f*_rn distance ops (((dx*dx+dy*dy)+dz*dz)), u64 key
// (valuebits<<32 | (lobase-(bj<<9))) = larger value wins / tie -> smaller
// index, 3-slot LDS atomicMax rotation, LDS-broadcast centroid.
// Two changes vs round 6 (each proven equivalent):
//  * value-only in-loop tracking (tmax via fminf/fmaxf); the thread's FIRST
//    index attaining tmax is recovered post-loop by a descending-j overwrite
//    scan (tmax is bitwise one of MD[j]; squares >= +0; no NaN).
//  * wave reduce via 6-step DPP (quad_perm xor1/xor2, row_shr:4/8,
//    row_bcast:15/31) -> lane 63 holds wave max (rocPRIM pattern), replacing
//    the 12-ds_bpermute shfl butterfly.
__global__ __launch_bounds__(512) void fps_kernel(const float* __restrict__ xyz,
                                                  float* __restrict__ newxyz){
  const int b = blockIdx.x, t = threadIdx.x;
  const float* px = xyz + (size_t)b * N_ * 3;
  __shared__ float pl[N_ * 3];                    // 96 KB copy of the batch
  __shared__ unsigned long long slot[3];

  // coalesced global -> LDS copy
  for (int i = t; i < N_ * 3 / 4; i += 512)
    ((float4*)pl)[i] = ((const float4*)px)[i];

  float X[16], Y[16], Z[16], MD[16];
#pragma unroll
  for (int j = 0; j < 16; j++){
    int p = j * 512 + t;
    X[j] = px[3 * p]; Y[j] = px[3 * p + 1]; Z[j] = px[3 * p + 2];
    MD[j] = 1e10f;
    asm volatile("" : "+v"(X[j]), "+v"(Y[j]), "+v"(Z[j]));   // pin in VGPRs
  }
  if (t == 0){
    slot[0] = 0ull; slot[1] = 0ull; slot[2] = 0ull;
    size_t o = (size_t)b * S_ * 3;
    newxyz[o] = px[0]; newxyz[o + 1] = px[1]; newxyz[o + 2] = px[2];
  }
  float cx = px[0], cy = px[1], cz = px[2];
  __syncthreads();                                // covers pl copy + slot init

  int cur = 1;                                    // slot index = i % 3
  const unsigned lobase = 8191u - (unsigned)t;
  for (int i = 1; i < S_; i++){
    float tmax = -1.f;
#pragma unroll
    for (int j = 0; j < 16; j++){
      float dx = __fsub_rn(X[j], cx);
      float dy = __fsub_rn(Y[j], cy);
      float dz = __fsub_rn(Z[j], cz);
      float d  = __fadd_rn(__fadd_rn(__fmul_rn(dx, dx), __fmul_rn(dy, dy)), __fmul_rn(dz, dz));
      float m  = fminf(MD[j], d);
      MD[j] = m;
      tmax = fmaxf(tmax, m);
    }
    // recover this thread's FIRST (smallest-j) index attaining tmax:
    // descending scan, later (smaller-j) assignments overwrite.
    int bj = 0;
#pragma unroll
    for (int j = 15; j >= 0; j--)
      if (MD[j] == tmax) bj = j;
    // key: larger value wins; tie -> larger (8191-idx) -> smaller idx.
    // tmax >= 0 so float bits are order-preserving as uint.
    unsigned long long key = ((unsigned long long)__float_as_uint(tmax) << 32)
                           | (unsigned long long)(lobase - (unsigned)(bj << 9));
    // wave64 DPP reduce -> lane 63 holds the wave max
    key = u64max(key, dpp64<0xb1>(key));          // quad_perm [1,0,3,2]
    key = u64max(key, dpp64<0x4e>(key));          // quad_perm [2,3,0,1]
    key = u64max(key, dpp64<0x114>(key));         // row_shr:4
    key = u64max(key, dpp64<0x118>(key));         // row_shr:8
    key = u64max(key, dpp64<0x142>(key));         // row_bcast:15
    key = u64max(key, dpp64<0x143>(key));         // row_bcast:31
    if ((t & 63) == 63) atomicMax(&slot[cur], key);   // 1 atomic per wave
    const int nxt = (cur == 2) ? 0 : cur + 1;
    if (t == 0) slot[nxt] = 0ull;   // zeroed pre-barrier; used next iter post-barrier
    __syncthreads();
    const unsigned long long best = slot[cur];
    const int fi = 8191 - (int)(best & 0xffffu);
    cx = pl[3 * fi]; cy = pl[3 * fi + 1]; cz = pl[3 * fi + 2];  // LDS broadcast
    if (t == 0){
      size_t o = ((size_t)b * S_ + i) * 3;
      newxyz[o] = cx; newxyz[o + 1] = cy; newxyz[o + 2] = cz;
    }
    cur = nxt;
  }
}

// ---- ball query: 1 wave per centroid ----
__global__ __launch_bounds__(256) void ballq_kernel(const float* __restrict__ xyz,
                                                    const float* __restrict__ newxyz,
                                                    int* __restrict__ idxout){
  const int wave = threadIdx.x >> 6, lane = threadIdx.x & 63;
  const int cid = blockIdx.x * 4 + wave;
  const int b = cid >> 10;
  const float cx = newxyz[(size_t)cid * 3];
  const float cy = newxyz[(size_t)cid * 3 + 1];
  const float cz = newxyz[(size_t)cid * 3 + 2];
  const float* px = xyz + (size_t)b * N_ * 3;
  __shared__ int buf[4][32];
  const float r2 = 0.04f;   // fp32(double(0.2*0.2)) == 0x3D23D70A
  int have = 0;
  for (int base = 0; base < N_ && have < 32; base += 64){
    int p = base + lane;
    float dx = __fsub_rn(cx, px[3 * p]);
    float dy = __fsub_rn(cy, px[3 * p + 1]);
    float dz = __fsub_rn(cz, px[3 * p + 2]);
    float sq = __fadd_rn(__fadd_rn(__fmul_rn(dx, dx), __fmul_rn(dy, dy)), __fmul_rn(dz, dz));
    bool pred = sq < r2;
    unsigned long long m = __ballot(pred);
    if (pred){
      int pos = have + __popcll(m & ((1ull << lane) - 1ull));
      if (pos < 32) buf[wave][pos] = p;
    }
    have += (int)__popcll(m);
  }
  __syncthreads();
  if (lane < 32){
    int first = buf[wave][0];
    int v = (lane < have) ? buf[wave][lane] : first;
    idxout[(size_t)cid * 32 + lane] = v;
  }
}

// ---- LDS arena layout for the recompute pass kernels ----
template<int DEPTH>
struct PassLds {
  static constexpr int XS  = 0;                 // [32][36] f32 (x tile, col35 zeroed)
  static constexpr int W1O = XS + 32 * 36;      // [64][36] f32 (col35 zeroed)
  static constexpr int HA  = W1O + 64 * 36;     // [32][68] f32 (DEPTH>=2)
  static constexpr int W2O = HA + 32 * 68;      // [64][64] f32
  static constexpr int HB  = W2O + 64 * 64;     // [32][68] f32 (DEPTH==3)
  static constexpr int W3O = HB + 32 * 68;      // [128][64] bf16 -> 4096 f32 slots
  static constexpr int FLOATS = (DEPTH == 1) ? (W1O + 64 * 36)
                             : (DEPTH == 2) ? (W2O + 64 * 64)
                             : (W3O + 4096);    // D3: 16000 floats = 64000 B
};

// ---- fused recompute pass (512 threads: row = t&31, grp = t>>5 in [0,16)) ----
template<int DEPTH, bool FT>
__global__ __launch_bounds__(512) void pass_kernel(
    const float* __restrict__ xyz, const float* __restrict__ feat,
    const unsigned short* __restrict__ featT, const float* __restrict__ newxyz,
    const int* __restrict__ idx,
    const float* __restrict__ W1, const float* __restrict__ W2,
    const float* __restrict__ W3,
    const float* __restrict__ sab1, const float* __restrict__ sab2,
    float* __restrict__ partials,
    unsigned short* __restrict__ m3max, unsigned short* __restrict__ m3min){
  using L = PassLds<DEPTH>;
  __shared__ float sm[L::FLOATS];
  const int t = threadIdx.x;
  const int row = t & 31, grp = t >> 5;   // sample-row, channel-group

  // ---- stage weights once per block ----
  for (int i = t; i < 64 * 36; i += 512){
    int o = i / 36, c = i - o * 36;
    sm[L::W1O + i] = (c < 35) ? W1[o * 35 + c] : 0.f;
  }
  if constexpr (DEPTH >= 2){
    for (int i = t; i < 64 * 64; i += 512) sm[L::W2O + i] = W2[i];
  }
  unsigned short* w3p = nullptr;
  if constexpr (DEPTH == 3){
    w3p = (unsigned short*)&sm[L::W3O];
    for (int i = t; i < 128 * 64; i += 512) w3p[i] = f2bf(W3[i]);
  }

  // ---- per-thread BN params ----
  float sa1[4], sb1[4], sa2[4], sb2[4];
  if constexpr (DEPTH >= 2){
#pragma unroll
    for (int u = 0; u < 4; u++){ sa1[u] = sab1[grp * 4 + u]; sb1[u] = sab1[64 + grp * 4 + u]; }
  }
  if constexpr (DEPTH == 3){
#pragma unroll
    for (int u = 0; u < 4; u++){ sa2[u] = sab2[grp * 4 + u]; sb2[u] = sab2[64 + grp * 4 + u]; }
  }

  constexpr int US = (DEPTH == 3) ? 8 : 4;     // stats channels per thread
  float stS[US], stQ[US];
#pragma unroll
  for (int u = 0; u < US; u++){ stS[u] = 0.f; stQ[u] = 0.f; }

  for (int it = 0; it < 32; ++it){
    const int g = blockIdx.x * 32 + it;
    const int b = g >> 10;
    if constexpr (DEPTH == 1) __syncthreads();  // protect XS from prev readers

    // ---- gather x tile: [32 pts][3 rel-coords | 32 feats | 0 pad] ----
    {
      float* xr = &sm[L::XS + row * 36];
      if constexpr (FT){
        if (grp < 4){
          const int id = idx[(size_t)g * 32 + row];
          const uint4 f = *(const uint4*)(featT + ((size_t)b * N_ + id) * C_ + grp * 8);
          xr[3 + grp * 8 + 0] = bflo(f.x); xr[3 + grp * 8 + 1] = bfhi(f.x);
          xr[3 + grp * 8 + 2] = bflo(f.y); xr[3 + grp * 8 + 3] = bfhi(f.y);
          xr[3 + grp * 8 + 4] = bflo(f.z); xr[3 + grp * 8 + 5] = bfhi(f.z);
          xr[3 + grp * 8 + 6] = bflo(f.w); xr[3 + grp * 8 + 7] = bfhi(f.w);
        } else if (grp == 4){
          const int id = idx[(size_t)g * 32 + row];
          size_t pb = ((size_t)b * N_ + id) * 3;
          xr[0] = __fsub_rn(xyz[pb + 0], newxyz[(size_t)g * 3 + 0]);
          xr[1] = __fsub_rn(xyz[pb + 1], newxyz[(size_t)g * 3 + 1]);
          xr[2] = __fsub_rn(xyz[pb + 2], newxyz[(size_t)g * 3 + 2]);
          xr[35] = 0.f;
        }
      } else {
        if (grp < 8){
          const int id = idx[(size_t)g * 32 + row];
#pragma unroll
          for (int q = 0; q < 4; q++)
            xr[3 + grp * 4 + q] = feat[((size_t)b * C_ + grp * 4 + q) * N_ + id];
        } else if (grp == 8){
          const int id = idx[(size_t)g * 32 + row];
          size_t pb = ((size_t)b * N_ + id) * 3;
          xr[0] = __fsub_rn(xyz[pb + 0], newxyz[(size_t)g * 3 + 0]);
          xr[1] = __fsub_rn(xyz[pb + 1], newxyz[(size_t)g * 3 + 1]);
          xr[2] = __fsub_rn(xyz[pb + 2], newxyz[(size_t)g * 3 + 2]);
          xr[35] = 0.f;
        }
      }
    }
    __syncthreads();

    // ---- mm1: y1[row][grp*4+u] ----
    float acc[4] = {0.f, 0.f, 0.f, 0.f};
#pragma unroll 3
    for (int cb = 0; cb < 36; cb += 4){
      const float4 xv = *(const float4*)&sm[L::XS + row * 36 + cb];
#pragma unroll
      for (int u = 0; u < 4; u++){
        const float4 wv = *(const float4*)&sm[L::W1O + (grp * 4 + u) * 36 + cb];
        acc[u] = fmaf(xv.x, wv.x, acc[u]);
        acc[u] = fmaf(xv.y, wv.y, acc[u]);
        acc[u] = fmaf(xv.z, wv.z, acc[u]);
        acc[u] = fmaf(xv.w, wv.w, acc[u]);
      }
    }
    if constexpr (DEPTH == 1){
#pragma unroll
      for (int u = 0; u < 4; u++){ stS[u] += acc[u]; stQ[u] = fmaf(acc[u], acc[u], stQ[u]); }
      continue;
    }

    if constexpr (DEPTH >= 2){
      // ---- bn1 + relu -> hA ----
#pragma unroll
      for (int u = 0; u < 4; u++)
        sm[L::HA + row * 68 + grp * 4 + u] = fmaxf(fmaf(acc[u], sa1[u], sb1[u]), 0.f);
      __syncthreads();

      // ---- mm2 ----
      float acc2[4] = {0.f, 0.f, 0.f, 0.f};
#pragma unroll 4
      for (int cb = 0; cb < 64; cb += 4){
        const float4 xv = *(const float4*)&sm[L::HA + row * 68 + cb];
#pragma unroll
        for (int u = 0; u < 4; u++){
          const float4 wv = *(const float4*)&sm[L::W2O + (grp * 4 + u) * 64 + cb];
          acc2[u] = fmaf(xv.x, wv.x, acc2[u]);
          acc2[u] = fmaf(xv.y, wv.y, acc2[u]);
          acc2[u] = fmaf(xv.z, wv.z, acc2[u]);
          acc2[u] = fmaf(xv.w, wv.w, acc2[u]);
        }
      }
      if constexpr (DEPTH == 2){
#pragma unroll
        for (int u = 0; u < 4; u++){ stS[u] += acc2[u]; stQ[u] = fmaf(acc2[u], acc2[u], stQ[u]); }
        continue;
      }

      if constexpr (DEPTH == 3){
        // ---- bn2 + relu -> hB ----
#pragma unroll
        for (int u = 0; u < 4; u++)
          sm[L::HB + row * 68 + grp * 4 + u] = fmaxf(fmaf(acc2[u], sa2[u], sb2[u]), 0.f);
        __syncthreads();

        // ---- mm3: y3[row][grp*8+u], W3 bf16 in LDS ----
        float acc3[8];
#pragma unroll
        for (int u = 0; u < 8; u++) acc3[u] = 0.f;
#pragma unroll 2
        for (int cb = 0; cb < 64; cb += 4){
          const float4 xv = *(const float4*)&sm[L::HB + row * 68 + cb];
#pragma unroll
          for (int u = 0; u < 8; u++){
            const uint2 wp = *(const uint2*)&w3p[(grp * 8 + u) * 64 + cb];
            acc3[u] = fmaf(xv.x, bflo(wp.x), acc3[u]);
            acc3[u] = fmaf(xv.y, bfhi(wp.x), acc3[u]);
            acc3[u] = fmaf(xv.z, bflo(wp.y), acc3[u]);
            acc3[u] = fmaf(xv.w, bfhi(wp.y), acc3[u]);
          }
        }
#pragma unroll
        for (int u = 0; u < 8; u++){ stS[u] += acc3[u]; stQ[u] = fmaf(acc3[u], acc3[u], stQ[u]); }

        // ---- pre-BN max/min over the 32 rows (lanes within half-wave) ----
        const int s = g & 1023;
#pragma unroll
        for (int u = 0; u < 8; u++){
          float mx = acc3[u], mn = acc3[u];
#pragma unroll
          for (int m = 1; m < 32; m <<= 1){
            mx = fmaxf(mx, __shfl_xor(mx, m));
            mn = fminf(mn, __shfl_xor(mn, m));
          }
          if (row == 0){
            size_t o = ((size_t)b * 128 + grp * 8 + u) * 1024 + s;
            m3max[o] = f2bf(mx); m3min[o] = f2bf(mn);
          }
        }
      }
    }
  }

  // ---- block stats partials: reduce over rows (half-wave lanes) ----
#pragma unroll
  for (int m = 1; m < 32; m <<= 1){
#pragma unroll
    for (int u = 0; u < US; u++){
      stS[u] += __shfl_xor(stS[u], m);
      stQ[u] += __shfl_xor(stQ[u], m);
    }
  }
  if (row == 0){
    constexpr int CH = (DEPTH == 3) ? 128 : 64;
    float* p = partials + (size_t)blockIdx.x * (2 * CH);
    const int o0 = grp * US;
#pragma unroll
    for (int u = 0; u < US; u++){ p[o0 + u] = stS[u]; p[CH + o0 + u] = stQ[u]; }
  }
}

// ---- stats stage 2: reduce 512 partial rows, emit per-channel scale/shift ----
template<int CH>
__global__ __launch_bounds__(256) void stats_fin(const float* __restrict__ partials,
                                                 const float* __restrict__ g,
                                                 const float* __restrict__ bet,
                                                 float* __restrict__ sab){
  const int t = threadIdx.x;
  __shared__ float red[2 * CH];
  if (t < 2 * CH){
    float a = 0.f;
#pragma unroll 8
    for (int r = 0; r < 512; r++) a += partials[(size_t)r * (2 * CH) + t];
    red[t] = a;
  }
  __syncthreads();
  if (t < CH){
    constexpr float inv = 1.f / (float)((size_t)B_ * S_ * K_);
    float mean = red[t] * inv;
    float var  = red[CH + t] * inv - mean * mean;
    float r    = 1.f / sqrtf(var + BN_EPS_);
    float a    = r * g[t];
    sab[t] = a;
    sab[CH + t] = bet[t] - mean * a;
  }
}

// ---- final: bn3(+relu) on bf16 pre-BN max/min (monotone-affine dispatch) ----
__global__ __launch_bounds__(256) void final_kernel(const unsigned short* __restrict__ m3max,
                                                    const unsigned short* __restrict__ m3min,
                                                    const float* __restrict__ sab3,
                                                    float* __restrict__ outNF){
  const int q = blockIdx.x * 256 + threadIdx.x;   // quad index over B*128*1024/4
  const int e = q * 4;
  const int o = (e >> 10) & 127;
  const float a = sab3[o], c = sab3[128 + o];
  const ushort4 mx = ((const ushort4*)m3max)[q];
  const ushort4 mn = ((const ushort4*)m3min)[q];
  float4 r;
  r.x = fmaxf(fmaf(bfu(a >= 0.f ? mx.x : mn.x), a, c), 0.f);
  r.y = fmaxf(fmaf(bfu(a >= 0.f ? mx.y : mn.y), a, c), 0.f);
  r.z = fmaxf(fmaf(bfu(a >= 0.f ? mx.z : mn.z), a, c), 0.f);
  r.w = fmaxf(fmaf(bfu(a >= 0.f ? mx.w : mn.w), a, c), 0.f);
  ((float4*)outNF)[q] = r;
}

extern "C" void kernel_launch(void* const* d_in, const int* in_sizes, int n_in,
                              void* d_out, int out_size, void* d_ws, size_t ws_size,
                              hipStream_t stream){
  (void)in_sizes; (void)n_in; (void)out_size;
  const float* xyz = (const float*)d_in[0];
  const float* feat = (const float*)d_in[1];
  const float* W1 = (const float*)d_in[2];
  const float* g1 = (const float*)d_in[3];
  const float* b1 = (const float*)d_in[4];
  const float* W2 = (const float*)d_in[5];
  const float* g2 = (const float*)d_in[6];
  const float* b2 = (const float*)d_in[7];
  const float* W3 = (const float*)d_in[8];
  const float* g3 = (const float*)d_in[9];
  const float* b3 = (const float*)d_in[10];

  float* newxyz = (float*)d_out;                       // (B,S,3)
  float* outNF  = newxyz + (size_t)B_ * S_ * 3;        // (B,128,S)
  char* ws = (char*)d_ws;

  size_t off = 0;
  auto alloc = [&](size_t bytes){ size_t o = off; off += (bytes + 255) & ~(size_t)255; return o; };
  size_t o_idx  = alloc((size_t)B_ * S_ * K_ * 4);           // 2 MB
  size_t o_part = alloc((size_t)512 * 256 * 4);              // 512 KB
  size_t o_sab1 = alloc(1024);
  size_t o_sab2 = alloc(1024);
  size_t o_sab3 = alloc(1024);
  size_t o_m3mx = alloc((size_t)B_ * S_ * 128 * 2);          // 4 MB (bf16)
  size_t o_m3mn = alloc((size_t)B_ * S_ * 128 * 2);          // 4 MB (bf16)
  size_t o_featT = alloc((size_t)B_ * N_ * C_ * 2);          // 8 MB (bf16)
  const bool ft = ws_size >= off;                            // 19.4 MB total

  int*   idxp  = (int*)(ws + o_idx);
  float* part  = (float*)(ws + o_part);
  float* sab1  = (float*)(ws + o_sab1);
  float* sab2  = (float*)(ws + o_sab2);
  float* sab3  = (float*)(ws + o_sab3);
  unsigned short* m3mx  = (unsigned short*)(ws + o_m3mx);
  unsigned short* m3mn  = (unsigned short*)(ws + o_m3mn);
  unsigned short* featT = (unsigned short*)(ws + o_featT);

  if (ft) transpose_kernel<<<dim3(N_ / 32, B_), dim3(32, 8), 0, stream>>>(feat, featT);
  fps_kernel<<<B_, 512, 0, stream>>>(xyz, newxyz);
  ballq_kernel<<<B_ * S_ / 4, 256, 0, stream>>>(xyz, newxyz, idxp);

  if (ft){
    pass_kernel<1, true><<<512, 512, 0, stream>>>(xyz, feat, featT, newxyz, idxp,
        W1, W2, W3, sab1, sab2, part, m3mx, m3mn);
    stats_fin<64><<<1, 256, 0, stream>>>(part, g1, b1, sab1);
    pass_kernel<2, true><<<512, 512, 0, stream>>>(xyz, feat, featT, newxyz, idxp,
        W1, W2, W3, sab1, sab2, part, m3mx, m3mn);
    stats_fin<64><<<1, 256, 0, stream>>>(part, g2, b2, sab2);
    pass_kernel<3, true><<<512, 512, 0, stream>>>(xyz, feat, featT, newxyz, idxp,
        W1, W2, W3, sab1, sab2, part, m3mx, m3mn);
    stats_fin<128><<<1, 256, 0, stream>>>(part, g3, b3, sab3);
  } else {
    pass_kernel<1, false><<<512, 512, 0, stream>>>(xyz, feat, featT, newxyz, idxp,
        W1, W2, W3, sab1, sab2, part, m3mx, m3mn);
    stats_fin<64><<<1, 256, 0, stream>>>(part, g1, b1, sab1);
    pass_kernel<2, false><<<512, 512, 0, stream>>>(xyz, feat, featT, newxyz, idxp,
        W1, W2, W3, sab1, sab2, part, m3mx, m3mn);
    stats_fin<64><<<1, 256, 0, stream>>>(part, g2, b2, sab2);
    pass_kernel<3, false><<<512, 512, 0, stream>>>(xyz, feat, featT, newxyz, idxp,
        W1, W2, W3, sab1, sab2, part, m3mx, m3mn);
    stats_fin<128><<<1, 256, 0, stream>>>(part, g3, b3, sab3);
  }
  final_kernel<<<(B_ * 128 * S_) / 1024, 256, 0, stream>>>(m3mx, m3mn, sab3, outNF);
}

// Round 10
// 1750.502 us; speedup vs baseline: 2.4521x; 1.0253x over previous
//
#include <hip/hip_runtime.h>
#include <hip/hip_bf16.h>

// ---- problem constants ----
static constexpr int B_ = 16;
static constexpr int N_ = 8192;
static constexpr int C_ = 32;     // input feature channels
static constexpr int S_ = 1024;   // NPOINT
static constexpr int K_ = 32;     // NSAMPLE
static constexpr float BN_EPS_ = 1e-5f;

typedef float f32x2 __attribute__((ext_vector_type(2)));

__device__ __forceinline__ unsigned short f2bf(float f){
  unsigned u = __float_as_uint(f);
  unsigned r = (u + 0x7fffu + ((u >> 16) & 1u)) >> 16;
  return (unsigned short)r;
}
__device__ __forceinline__ float bflo(unsigned u){ return __int_as_float(u << 16); }
__device__ __forceinline__ float bfhi(unsigned u){ return __int_as_float(u & 0xffff0000u); }
__device__ __forceinline__ float bfu(unsigned short u){ return __int_as_float(((unsigned)u) << 16); }

// rocPRIM-standard wave64 DPP reduce step on a u64 key (HW-proven round 9).
template<int CTRL>
__device__ __forceinline__ unsigned long long dpp64(unsigned long long v){
  int lo = (int)(unsigned)(v & 0xffffffffull);
  int hi = (int)(unsigned)(v >> 32);
  int lo2 = __builtin_amdgcn_update_dpp(lo, lo, CTRL, 0xf, 0xf, false);
  int hi2 = __builtin_amdgcn_update_dpp(hi, hi, CTRL, 0xf, 0xf, false);
  return (((unsigned long long)(unsigned)hi2) << 32) | (unsigned)lo2;
}
__device__ __forceinline__ unsigned long long u64max(unsigned long long a,
                                                     unsigned long long b){
  return a > b ? a : b;
}

// ---- features (B,C,N) f32 -> featT (B,N,C) bf16 ----
__global__ __launch_bounds__(256) void transpose_kernel(const float* __restrict__ feat,
                                                        unsigned short* __restrict__ featT){
  __shared__ float tile[32][33];
  const int b = blockIdx.y;
  const int n0 = blockIdx.x * 32;
  const int tx = threadIdx.x, ty = threadIdx.y;
#pragma unroll
  for (int i = 0; i < 4; i++){
    int c = ty + i * 8;
    tile[c][tx] = feat[((size_t)b * C_ + c) * N_ + n0 + tx];
  }
  __syncthreads();
#pragma unroll
  for (int i = 0; i < 4; i++){
    int r = ty + i * 8;
    featT[((size_t)b * N_ + n0 + r) * C_ + tx] = f2bf(tile[tx][r]);
  }
}

// ---- furthest point sampling: 1 block/batch, 1 barrier/iter ----
// Round-9 HW-proven skeleton (u64 key, 3-slot LDS atomicMax rotation, DPP
// reduce, LDS-broadcast centroid, value-only tracking + descending recovery
// scan). This round: distance math on f32x2 pairs — plain C vector ops only
// (per-half IEEE rn, bitwise equal to scalar __f*_rn chain regardless of
// packed-vs-scalar lowering). Pins applied to SCALARS ONLY, then vectors are
// assembled from pinned values (the R7/R8 failure was "+v" pins on 64-bit
// vector operands; scalar pins are R6/R9-proven).
__global__ __launch_bounds__(512) void fps_kernel(const float* __restrict__ xyz,
                                                  float* __restrict__ newxyz){
  const int b = blockIdx.x, t = threadIdx.x;
  const float* px = xyz + (size_t)b * N_ * 3;
  __shared__ float pl[N_ * 3];                    // 96 KB copy of the batch
  __shared__ unsigned long long slot[3];

  // coalesced global -> LDS copy
  for (int i = t; i < N_ * 3 / 4; i += 512)
    ((float4*)pl)[i] = ((const float4*)px)[i];

  f32x2 X2[8], Y2[8], Z2[8], MD2[8];
#pragma unroll
  for (int q = 0; q < 8; q++){
    const int p0 = 1024 * q + t, p1 = 1024 * q + 512 + t;
    float x0 = px[3 * p0 + 0], y0 = px[3 * p0 + 1], z0 = px[3 * p0 + 2];
    float x1 = px[3 * p1 + 0], y1 = px[3 * p1 + 1], z1 = px[3 * p1 + 2];
    asm volatile("" : "+v"(x0), "+v"(y0), "+v"(z0),
                      "+v"(x1), "+v"(y1), "+v"(z1));   // pin SCALARS in VGPRs
    X2[q] = f32x2{x0, x1};
    Y2[q] = f32x2{y0, y1};
    Z2[q] = f32x2{z0, z1};
    MD2[q] = f32x2{1e10f, 1e10f};
  }
  if (t == 0){
    slot[0] = 0ull; slot[1] = 0ull; slot[2] = 0ull;
    size_t o = (size_t)b * S_ * 3;
    newxyz[o] = px[0]; newxyz[o + 1] = px[1]; newxyz[o + 2] = px[2];
  }
  float cx = px[0], cy = px[1], cz = px[2];
  __syncthreads();                                // covers pl copy + slot init

  int cur = 1;                                    // slot index = i % 3
  for (int i = 1; i < S_; i++){
    const f32x2 cx2 = {cx, cx}, cy2 = {cy, cy}, cz2 = {cz, cz};
    f32x2 tm2 = {-1.f, -1.f};
#pragma unroll
    for (int q = 0; q < 8; q++){
      f32x2 dx = X2[q] - cx2;                     // per-half rn sub
      f32x2 dy = Y2[q] - cy2;
      f32x2 dz = Z2[q] - cz2;
      f32x2 dd = (dx * dx + dy * dy) + dz * dz;   // exact reference op order
      f32x2 m;
      m[0] = fminf(MD2[q][0], dd[0]);
      m[1] = fminf(MD2[q][1], dd[1]);
      MD2[q] = m;
      tm2[0] = fmaxf(tm2[0], m[0]);
      tm2[1] = fmaxf(tm2[1], m[1]);
    }
    const float tmax = fmaxf(tm2[0], tm2[1]);
    // recover this thread's FIRST (smallest global) index attaining tmax:
    // descending q, high half (bigger idx) before low half -> later (smaller)
    // assignments overwrite.
    unsigned cand = 0;
#pragma unroll
    for (int q = 7; q >= 0; q--){
      if (MD2[q][1] == tmax) cand = (unsigned)(1024 * q + 512 + t);
      if (MD2[q][0] == tmax) cand = (unsigned)(1024 * q + t);
    }
    // key: larger value wins; tie -> larger (8191-idx) -> smaller idx.
    unsigned long long key = ((unsigned long long)__float_as_uint(tmax) << 32)
                           | (unsigned long long)(8191u - cand);
    // wave64 DPP reduce -> lane 63 holds the wave max
    key = u64max(key, dpp64<0xb1>(key));          // quad_perm [1,0,3,2]
    key = u64max(key, dpp64<0x4e>(key));          // quad_perm [2,3,0,1]
    key = u64max(key, dpp64<0x114>(key));         // row_shr:4
    key = u64max(key, dpp64<0x118>(key));         // row_shr:8
    key = u64max(key, dpp64<0x142>(key));         // row_bcast:15
    key = u64max(key, dpp64<0x143>(key));         // row_bcast:31
    if ((t & 63) == 63) atomicMax(&slot[cur], key);   // 1 atomic per wave
    const int nxt = (cur == 2) ? 0 : cur + 1;
    if (t == 0) slot[nxt] = 0ull;   // zeroed pre-barrier; used next iter post-barrier
    __syncthreads();
    const unsigned long long best = slot[cur];
    const int fi = 8191 - (int)(best & 0xffffu);
    cx = pl[3 * fi]; cy = pl[3 * fi + 1]; cz = pl[3 * fi + 2];  // LDS broadcast
    if (t == 0){
      size_t o = ((size_t)b * S_ + i) * 3;
      newxyz[o] = cx; newxyz[o + 1] = cy; newxyz[o + 2] = cz;
    }
    cur = nxt;
  }
}

// ---- ball query: 1 wave per centroid ----
__global__ __launch_bounds__(256) void ballq_kernel(const float* __restrict__ xyz,
                                                    const float* __restrict__ newxyz,
                                                    int* __restrict__ idxout){
  const int wave = threadIdx.x >> 6, lane = threadIdx.x & 63;
  const int cid = blockIdx.x * 4 + wave;
  const int b = cid >> 10;
  const float cx = newxyz[(size_t)cid * 3];
  const float cy = newxyz[(size_t)cid * 3 + 1];
  const float cz = newxyz[(size_t)cid * 3 + 2];
  const float* px = xyz + (size_t)b * N_ * 3;
  __shared__ int buf[4][32];
  const float r2 = 0.04f;   // fp32(double(0.2*0.2)) == 0x3D23D70A
  int have = 0;
  for (int base = 0; base < N_ && have < 32; base += 64){
    int p = base + lane;
    float dx = __fsub_rn(cx, px[3 * p]);
    float dy = __fsub_rn(cy, px[3 * p + 1]);
    float dz = __fsub_rn(cz, px[3 * p + 2]);
    float sq = __fadd_rn(__fadd_rn(__fmul_rn(dx, dx), __fmul_rn(dy, dy)), __fmul_rn(dz, dz));
    bool pred = sq < r2;
    unsigned long long m = __ballot(pred);
    if (pred){
      int pos = have + __popcll(m & ((1ull << lane) - 1ull));
      if (pos < 32) buf[wave][pos] = p;
    }
    have += (int)__popcll(m);
  }
  __syncthreads();
  if (lane < 32){
    int first = buf[wave][0];
    int v = (lane < have) ? buf[wave][lane] : first;
    idxout[(size_t)cid * 32 + lane] = v;
  }
}

// ---- LDS arena layout for the recompute pass kernels ----
template<int DEPTH>
struct PassLds {
  static constexpr int XS  = 0;                 // [32][36] f32 (x tile, col35 zeroed)
  static constexpr int W1O = XS + 32 * 36;      // [64][36] f32 (col35 zeroed)
  static constexpr int HA  = W1O + 64 * 36;     // [32][68] f32 (DEPTH>=2)
  static constexpr int W2O = HA + 32 * 68;      // [64][64] f32
  static constexpr int HB  = W2O + 64 * 64;     // [32][68] f32 (DEPTH==3)
  static constexpr int W3O = HB + 32 * 68;      // [128][64] bf16 -> 4096 f32 slots
  static constexpr int FLOATS = (DEPTH == 1) ? (W1O + 64 * 36)
                             : (DEPTH == 2) ? (W2O + 64 * 64)
                             : (W3O + 4096);    // D3: 16000 floats = 64000 B
};

// ---- fused recompute pass (512 threads: row = t&31, grp = t>>5 in [0,16)) ----
template<int DEPTH, bool FT>
__global__ __launch_bounds__(512) void pass_kernel(
    const float* __restrict__ xyz, const float* __restrict__ feat,
    const unsigned short* __restrict__ featT, const float* __restrict__ newxyz,
    const int* __restrict__ idx,
    const float* __restrict__ W1, const float* __restrict__ W2,
    const float* __restrict__ W3,
    const float* __restrict__ sab1, const float* __restrict__ sab2,
    float* __restrict__ partials,
    unsigned short* __restrict__ m3max, unsigned short* __restrict__ m3min){
  using L = PassLds<DEPTH>;
  __shared__ float sm[L::FLOATS];
  const int t = threadIdx.x;
  const int row = t & 31, grp = t >> 5;   // sample-row, channel-group

  // ---- stage weights once per block ----
  for (int i = t; i < 64 * 36; i += 512){
    int o = i / 36, c = i - o * 36;
    sm[L::W1O + i] = (c < 35) ? W1[o * 35 + c] : 0.f;
  }
  if constexpr (DEPTH >= 2){
    for (int i = t; i < 64 * 64; i += 512) sm[L::W2O + i] = W2[i];
  }
  unsigned short* w3p = nullptr;
  if constexpr (DEPTH == 3){
    w3p = (unsigned short*)&sm[L::W3O];
    for (int i = t; i < 128 * 64; i += 512) w3p[i] = f2bf(W3[i]);
  }

  // ---- per-thread BN params ----
  float sa1[4], sb1[4], sa2[4], sb2[4];
  if constexpr (DEPTH >= 2){
#pragma unroll
    for (int u = 0; u < 4; u++){ sa1[u] = sab1[grp * 4 + u]; sb1[u] = sab1[64 + grp * 4 + u]; }
  }
  if constexpr (DEPTH == 3){
#pragma unroll
    for (int u = 0; u < 4; u++){ sa2[u] = sab2[grp * 4 + u]; sb2[u] = sab2[64 + grp * 4 + u]; }
  }

  constexpr int US = (DEPTH == 3) ? 8 : 4;     // stats channels per thread
  float stS[US], stQ[US];
#pragma unroll
  for (int u = 0; u < US; u++){ stS[u] = 0.f; stQ[u] = 0.f; }

  for (int it = 0; it < 32; ++it){
    const int g = blockIdx.x * 32 + it;
    const int b = g >> 10;
    if constexpr (DEPTH == 1) __syncthreads();  // protect XS from prev readers

    // ---- gather x tile: [32 pts][3 rel-coords | 32 feats | 0 pad] ----
    {
      float* xr = &sm[L::XS + row * 36];
      if constexpr (FT){
        if (grp < 4){
          const int id = idx[(size_t)g * 32 + row];
          const uint4 f = *(const uint4*)(featT + ((size_t)b * N_ + id) * C_ + grp * 8);
          xr[3 + grp * 8 + 0] = bflo(f.x); xr[3 + grp * 8 + 1] = bfhi(f.x);
          xr[3 + grp * 8 + 2] = bflo(f.y); xr[3 + grp * 8 + 3] = bfhi(f.y);
          xr[3 + grp * 8 + 4] = bflo(f.z); xr[3 + grp * 8 + 5] = bfhi(f.z);
          xr[3 + grp * 8 + 6] = bflo(f.w); xr[3 + grp * 8 + 7] = bfhi(f.w);
        } else if (grp == 4){
          const int id = idx[(size_t)g * 32 + row];
          size_t pb = ((size_t)b * N_ + id) * 3;
          xr[0] = __fsub_rn(xyz[pb + 0], newxyz[(size_t)g * 3 + 0]);
          xr[1] = __fsub_rn(xyz[pb + 1], newxyz[(size_t)g * 3 + 1]);
          xr[2] = __fsub_rn(xyz[pb + 2], newxyz[(size_t)g * 3 + 2]);
          xr[35] = 0.f;
        }
      } else {
        if (grp < 8){
          const int id = idx[(size_t)g * 32 + row];
#pragma unroll
          for (int q = 0; q < 4; q++)
            xr[3 + grp * 4 + q] = feat[((size_t)b * C_ + grp * 4 + q) * N_ + id];
        } else if (grp == 8){
          const int id = idx[(size_t)g * 32 + row];
          size_t pb = ((size_t)b * N_ + id) * 3;
          xr[0] = __fsub_rn(xyz[pb + 0], newxyz[(size_t)g * 3 + 0]);
          xr[1] = __fsub_rn(xyz[pb + 1], newxyz[(size_t)g * 3 + 1]);
          xr[2] = __fsub_rn(xyz[pb + 2], newxyz[(size_t)g * 3 + 2]);
          xr[35] = 0.f;
        }
      }
    }
    __syncthreads();

    // ---- mm1: y1[row][grp*4+u] ----
    float acc[4] = {0.f, 0.f, 0.f, 0.f};
#pragma unroll 3
    for (int cb = 0; cb < 36; cb += 4){
      const float4 xv = *(const float4*)&sm[L::XS + row * 36 + cb];
#pragma unroll
      for (int u = 0; u < 4; u++){
        const float4 wv = *(const float4*)&sm[L::W1O + (grp * 4 + u) * 36 + cb];
        acc[u] = fmaf(xv.x, wv.x, acc[u]);
        acc[u] = fmaf(xv.y, wv.y, acc[u]);
        acc[u] = fmaf(xv.z, wv.z, acc[u]);
        acc[u] = fmaf(xv.w, wv.w, acc[u]);
      }
    }
    if constexpr (DEPTH == 1){
#pragma unroll
      for (int u = 0; u < 4; u++){ stS[u] += acc[u]; stQ[u] = fmaf(acc[u], acc[u], stQ[u]); }
      continue;
    }

    if constexpr (DEPTH >= 2){
      // ---- bn1 + relu -> hA ----
#pragma unroll
      for (int u = 0; u < 4; u++)
        sm[L::HA + row * 68 + grp * 4 + u] = fmaxf(fmaf(acc[u], sa1[u], sb1[u]), 0.f);
      __syncthreads();

      // ---- mm2 ----
      float acc2[4] = {0.f, 0.f, 0.f, 0.f};
#pragma unroll 4
      for (int cb = 0; cb < 64; cb += 4){
        const float4 xv = *(const float4*)&sm[L::HA + row * 68 + cb];
#pragma unroll
        for (int u = 0; u < 4; u++){
          const float4 wv = *(const float4*)&sm[L::W2O + (grp * 4 + u) * 64 + cb];
          acc2[u] = fmaf(xv.x, wv.x, acc2[u]);
          acc2[u] = fmaf(xv.y, wv.y, acc2[u]);
          acc2[u] = fmaf(xv.z, wv.z, acc2[u]);
          acc2[u] = fmaf(xv.w, wv.w, acc2[u]);
        }
      }
      if constexpr (DEPTH == 2){
#pragma unroll
        for (int u = 0; u < 4; u++){ stS[u] += acc2[u]; stQ[u] = fmaf(acc2[u], acc2[u], stQ[u]); }
        continue;
      }

      if constexpr (DEPTH == 3){
        // ---- bn2 + relu -> hB ----
#pragma unroll
        for (int u = 0; u < 4; u++)
          sm[L::HB + row * 68 + grp * 4 + u] = fmaxf(fmaf(acc2[u], sa2[u], sb2[u]), 0.f);
        __syncthreads();

        // ---- mm3: y3[row][grp*8+u], W3 bf16 in LDS ----
        float acc3[8];
#pragma unroll
        for (int u = 0; u < 8; u++) acc3[u] = 0.f;
#pragma unroll 2
        for (int cb = 0; cb < 64; cb += 4){
          const float4 xv = *(const float4*)&sm[L::HB + row * 68 + cb];
#pragma unroll
          for (int u = 0; u < 8; u++){
            const uint2 wp = *(const uint2*)&w3p[(grp * 8 + u) * 64 + cb];
            acc3[u] = fmaf(xv.x, bflo(wp.x), acc3[u]);
            acc3[u] = fmaf(xv.y, bfhi(wp.x), acc3[u]);
            acc3[u] = fmaf(xv.z, bflo(wp.y), acc3[u]);
            acc3[u] = fmaf(xv.w, bfhi(wp.y), acc3[u]);
          }
        }
#pragma unroll
        for (int u = 0; u < 8; u++){ stS[u] += acc3[u]; stQ[u] = fmaf(acc3[u], acc3[u], stQ[u]); }

        // ---- pre-BN max/min over the 32 rows (lanes within half-wave) ----
        const int s = g & 1023;
#pragma unroll
        for (int u = 0; u < 8; u++){
          float mx = acc3[u], mn = acc3[u];
#pragma unroll
          for (int m = 1; m < 32; m <<= 1){
            mx = fmaxf(mx, __shfl_xor(mx, m));
            mn = fminf(mn, __shfl_xor(mn, m));
          }
          if (row == 0){
            size_t o = ((size_t)b * 128 + grp * 8 + u) * 1024 + s;
            m3max[o] = f2bf(mx); m3min[o] = f2bf(mn);
          }
        }
      }
    }
  }

  // ---- block stats partials: reduce over rows (half-wave lanes) ----
#pragma unroll
  for (int m = 1; m < 32; m <<= 1){
#pragma unroll
    for (int u = 0; u < US; u++){
      stS[u] += __shfl_xor(stS[u], m);
      stQ[u] += __shfl_xor(stQ[u], m);
    }
  }
  if (row == 0){
    constexpr int CH = (DEPTH == 3) ? 128 : 64;
    float* p = partials + (size_t)blockIdx.x * (2 * CH);
    const int o0 = grp * US;
#pragma unroll
    for (int u = 0; u < US; u++){ p[o0 + u] = stS[u]; p[CH + o0 + u] = stQ[u]; }
  }
}

// ---- stats stage 2: reduce 512 partial rows, emit per-channel scale/shift ----
template<int CH>
__global__ __launch_bounds__(256) void stats_fin(const float* __restrict__ partials,
                                                 const float* __restrict__ g,
                                                 const float* __restrict__ bet,
                                                 float* __restrict__ sab){
  const int t = threadIdx.x;
  __shared__ float red[2 * CH];
  if (t < 2 * CH){
    float a = 0.f;
#pragma unroll 8
    for (int r = 0; r < 512; r++) a += partials[(size_t)r * (2 * CH) + t];
    red[t] = a;
  }
  __syncthreads();
  if (t < CH){
    constexpr float inv = 1.f / (float)((size_t)B_ * S_ * K_);
    float mean = red[t] * inv;
    float var  = red[CH + t] * inv - mean * mean;
    float r    = 1.f / sqrtf(var + BN_EPS_);
    float a    = r * g[t];
    sab[t] = a;
    sab[CH + t] = bet[t] - mean * a;
  }
}

// ---- final: bn3(+relu) on bf16 pre-BN max/min (monotone-affine dispatch) ----
__global__ __launch_bounds__(256) void final_kernel(const unsigned short* __restrict__ m3max,
                                                    const unsigned short* __restrict__ m3min,
                                                    const float* __restrict__ sab3,
                                                    float* __restrict__ outNF){
  const int q = blockIdx.x * 256 + threadIdx.x;   // quad index over B*128*1024/4
  const int e = q * 4;
  const int o = (e >> 10) & 127;
  const float a = sab3[o], c = sab3[128 + o];
  const ushort4 mx = ((const ushort4*)m3max)[q];
  const ushort4 mn = ((const ushort4*)m3min)[q];
  float4 r;
  r.x = fmaxf(fmaf(bfu(a >= 0.f ? mx.x : mn.x), a, c), 0.f);
  r.y = fmaxf(fmaf(bfu(a >= 0.f ? mx.y : mn.y), a, c), 0.f);
  r.z = fmaxf(fmaf(bfu(a >= 0.f ? mx.z : mn.z), a, c), 0.f);
  r.w = fmaxf(fmaf(bfu(a >= 0.f ? mx.w : mn.w), a, c), 0.f);
  ((float4*)outNF)[q] = r;
}

extern "C" void kernel_launch(void* const* d_in, const int* in_sizes, int n_in,
                              void* d_out, int out_size, void* d_ws, size_t ws_size,
                              hipStream_t stream){
  (void)in_sizes; (void)n_in; (void)out_size;
  const float* xyz = (const float*)d_in[0];
  const float* feat = (const float*)d_in[1];
  const float* W1 = (const float*)d_in[2];
  const float* g1 = (const float*)d_in[3];
  const float* b1 = (const float*)d_in[4];
  const float* W2 = (const float*)d_in[5];
  const float* g2 = (const float*)d_in[6];
  const float* b2 = (const float*)d_in[7];
  const float* W3 = (const float*)d_in[8];
  const float* g3 = (const float*)d_in[9];
  const float* b3 = (const float*)d_in[10];

  float* newxyz = (float*)d_out;                       // (B,S,3)
  float* outNF  = newxyz + (size_t)B_ * S_ * 3;        // (B,128,S)
  char* ws = (char*)d_ws;

  size_t off = 0;
  auto alloc = [&](size_t bytes){ size_t o = off; off += (bytes + 255) & ~(size_t)255; return o; };
  size_t o_idx  = alloc((size_t)B_ * S_ * K_ * 4);           // 2 MB
  size_t o_part = alloc((size_t)512 * 256 * 4);              // 512 KB
  size_t o_sab1 = alloc(1024);
  size_t o_sab2 = alloc(1024);
  size_t o_sab3 = alloc(1024);
  size_t o_m3mx = alloc((size_t)B_ * S_ * 128 * 2);          // 4 MB (bf16)
  size_t o_m3mn = alloc((size_t)B_ * S_ * 128 * 2);          // 4 MB (bf16)
  size_t o_featT = alloc((size_t)B_ * N_ * C_ * 2);          // 8 MB (bf16)
  const bool ft = ws_size >= off;                            // 19.4 MB total

  int*   idxp  = (int*)(ws + o_idx);
  float* part  = (float*)(ws + o_part);
  float* sab1  = (float*)(ws + o_sab1);
  float* sab2  = (float*)(ws + o_sab2);
  float* sab3  = (float*)(ws + o_sab3);
  unsigned short* m3mx  = (unsigned short*)(ws + o_m3mx);
  unsigned short* m3mn  = (unsigned short*)(ws + o_m3mn);
  unsigned short* featT = (unsigned short*)(ws + o_featT);

  if (ft) transpose_kernel<<<dim3(N_ / 32, B_), dim3(32, 8), 0, stream>>>(feat, featT);
  fps_kernel<<<B_, 512, 0, stream>>>(xyz, newxyz);
  ballq_kernel<<<B_ * S_ / 4, 256, 0, stream>>>(xyz, newxyz, idxp);

  if (ft){
    pass_kernel<1, true><<<512, 512, 0, stream>>>(xyz, feat, featT, newxyz, idxp,
        W1, W2, W3, sab1, sab2, part, m3mx, m3mn);
    stats_fin<64><<<1, 256, 0, stream>>>(part, g1, b1, sab1);
    pass_kernel<2, true><<<512, 512, 0, stream>>>(xyz, feat, featT, newxyz, idxp,
        W1, W2, W3, sab1, sab2, part, m3mx, m3mn);
    stats_fin<64><<<1, 256, 0, stream>>>(part, g2, b2, sab2);
    pass_kernel<3, true><<<512, 512, 0, stream>>>(xyz, feat, featT, newxyz, idxp,
        W1, W2, W3, sab1, sab2, part, m3mx, m3mn);
    stats_fin<128><<<1, 256, 0, stream>>>(part, g3, b3, sab3);
  } else {
    pass_kernel<1, false><<<512, 512, 0, stream>>>(xyz, feat, featT, newxyz, idxp,
        W1, W2, W3, sab1, sab2, part, m3mx, m3mn);
    stats_fin<64><<<1, 256, 0, stream>>>(part, g1, b1, sab1);
    pass_kernel<2, false><<<512, 512, 0, stream>>>(xyz, feat, featT, newxyz, idxp,
        W1, W2, W3, sab1, sab2, part, m3mx, m3mn);
    stats_fin<64><<<1, 256, 0, stream>>>(part, g2, b2, sab2);
    pass_kernel<3, false><<<512, 512, 0, stream>>>(xyz, feat, featT, newxyz, idxp,
        W1, W2, W3, sab1, sab2, part, m3mx, m3mn);
    stats_fin<128><<<1, 256, 0, stream>>>(part, g3, b3, sab3);
  }
  final_kernel<<<(B_ * 128 * S_) / 1024, 256, 0, stream>>>(m3mx, m3mn, sab3, outNF);
}